// Round 4
// baseline (163.682 us; speedup 1.0000x reference)
//
#include <hip/hip_runtime.h>
#include <stdint.h>

typedef unsigned short ushort_t;
typedef __attribute__((ext_vector_type(8))) short short8;   // 8 x bf16 (4 VGPRs)
typedef __attribute__((ext_vector_type(4))) float floatx4;  // MFMA accum

#define SEQ_N 2048
#define SEQ_M 2048
#define DIM_D 128
#define DIM_V 128
#define BC 64    // keys per tile (OLD path)
#define BC2 32   // keys per tile (NEW path)

// ======================= common helpers =======================

#if __has_builtin(__builtin_amdgcn_exp2f)
#define EXP2F(x) __builtin_amdgcn_exp2f(x)
#else
#define EXP2F(x) exp2f(x)
#endif

template <int CTRL>
__device__ __forceinline__ float dpp_f(float x) {
  int xi = __builtin_bit_cast(int, x);
  int yi = __builtin_amdgcn_update_dpp(xi, xi, CTRL, 0xf, 0xf, false);
  return __builtin_bit_cast(float, yi);
}
__device__ __forceinline__ float rowmax16(float x) {
  x = fmaxf(x, dpp_f<0x128>(x));
  x = fmaxf(x, dpp_f<0x124>(x));
  x = fmaxf(x, dpp_f<0x122>(x));
  x = fmaxf(x, dpp_f<0x121>(x));
  return x;
}
__device__ __forceinline__ float rowsum16(float x) {
  x += dpp_f<0x128>(x);
  x += dpp_f<0x124>(x);
  x += dpp_f<0x122>(x);
  x += dpp_f<0x121>(x);
  return x;
}

__device__ __forceinline__ ushort_t f2bf(float f) {
  uint32_t u = __builtin_bit_cast(uint32_t, f);
  return (ushort_t)((u + 0x8000u) >> 16);
}
// pack two fp32 -> bf16 pair in ONE v_perm (3 VALU total, bit-identical to f2bf pair)
__device__ __forceinline__ uint32_t bfpack(float lo, float hi) {
  uint32_t a = __builtin_bit_cast(uint32_t, lo) + 0x8000u;
  uint32_t b = __builtin_bit_cast(uint32_t, hi) + 0x8000u;
  return __builtin_amdgcn_perm(b, a, 0x07060302u);  // {b[31:16], a[31:16]}
}

// ======================= NEW PATH =======================
// BM=64 rows/block, BC2=32 keys/tile, 256 threads (4 waves x 16 rows).
// LDS (ushort): K 2x[32][128] (8KB ea), Vt 2x[128][32] (8KB ea), P [64][32] (4KB)
// = 36864 B -> 4 blocks/CU. 1248 blocks on 1024 slots -> backfill.
// Chunking caps len at 17 tiles: nch(rt) = 1 (rt<=7), 2 (8..16), 3 (17..24), 4 (25..31).
#define K2OFF 0
#define V2OFF 8192
#define P2OFF 16384
#define SMEM2 18432
#define KELEMS 4096
#define VELEMS 4096

// ws layout (floats); gate constant unchanged (proven available); used = 8,286,208
#define WS2_VT 0             // Vt bf16 [16][128][2048]
#define WS2_PO 2097152       // 736 partial-O slots x 64x128 fp32
#define WS2_M  8126464       // 1248 chunks x 64 rows
#define WS2_L  8206336
#define WS2_FLOATS 8519680   // * 4 = 34078720 bytes (gate)

// async 16B global->LDS; lds_base must be wave-uniform (HW adds lane*16)
__device__ __forceinline__ void stage16(const ushort_t* src, ushort_t* lds_base, int lane) {
#if __has_builtin(__builtin_amdgcn_global_load_lds)
  __builtin_amdgcn_global_load_lds(
      (const __attribute__((address_space(1))) void*)src,
      (__attribute__((address_space(3))) void*)lds_base, 16, 0, 0);
#else
  *(uint4*)(lds_base + lane * 8) = *(const uint4*)src;
#endif
}

// prep: V -> bf16 transposed [b][v][m]  (K stays fp32, converted in fa2)
__global__ __launch_bounds__(256)
void prep2(const float* __restrict__ Vg, float* __restrict__ ws) {
  __shared__ __align__(16) ushort_t lt[64][72];
  ushort_t* Vt = (ushort_t*)(ws + WS2_VT);
  const int g = blockIdx.x, tid = threadIdx.x;   // g 0..1023
  const int b = g >> 6;
  const int mt = (g & 63) >> 1;
  const int vh = (g & 1) * 64;
  const int mrow = tid >> 2, v0 = (tid & 3) * 16;
  const float* p = Vg + ((size_t)b * SEQ_M + (size_t)(mt * 64 + mrow)) * DIM_V + vh + v0;
  float4 f0 = *(const float4*)p, f1 = *(const float4*)(p + 4);
  float4 f2 = *(const float4*)(p + 8), f3 = *(const float4*)(p + 12);
  lt[v0 +  0][mrow] = f2bf(f0.x); lt[v0 +  1][mrow] = f2bf(f0.y);
  lt[v0 +  2][mrow] = f2bf(f0.z); lt[v0 +  3][mrow] = f2bf(f0.w);
  lt[v0 +  4][mrow] = f2bf(f1.x); lt[v0 +  5][mrow] = f2bf(f1.y);
  lt[v0 +  6][mrow] = f2bf(f1.z); lt[v0 +  7][mrow] = f2bf(f1.w);
  lt[v0 +  8][mrow] = f2bf(f2.x); lt[v0 +  9][mrow] = f2bf(f2.y);
  lt[v0 + 10][mrow] = f2bf(f2.z); lt[v0 + 11][mrow] = f2bf(f2.w);
  lt[v0 + 12][mrow] = f2bf(f3.x); lt[v0 + 13][mrow] = f2bf(f3.y);
  lt[v0 + 14][mrow] = f2bf(f3.z); lt[v0 + 15][mrow] = f2bf(f3.w);
  __syncthreads();
  const int v = tid >> 2, mo = (tid & 3) * 16;
  ushort_t* dst = Vt + ((size_t)(b * DIM_V + vh + v) * SEQ_M) + mt * 64 + mo;
  *(uint4*)(dst + 0) = *(const uint4*)&lt[v][mo];
  *(uint4*)(dst + 8) = *(const uint4*)&lt[v][mo + 8];
}

// chunk-count helpers (causal)
__device__ __forceinline__ int nch_of(int rt) {
  return (rt <= 7) ? 1 : ((rt <= 16) ? 2 : ((rt <= 24) ? 3 : 4));
}
__device__ __forceinline__ int cbase_of(int rt) {   // cumsum of nch
  return (rt <= 7) ? rt
       : ((rt <= 16) ? (8 + 2 * (rt - 8))
       : ((rt <= 24) ? (26 + 3 * (rt - 17)) : (50 + 4 * (rt - 25))));
}
__device__ __forceinline__ int sbase_of(int rt) {   // cumsum of (nch-1)
  return (rt <= 7) ? 0
       : ((rt <= 16) ? (rt - 8)
       : ((rt <= 24) ? (9 + 2 * (rt - 17)) : (25 + 3 * (rt - 25))));
}

// 1248 wgs x 256 threads. idx 0..77 enumerates causal chunks rt-descending
// (longest ~17-tile chunks dispatch first; tail blocks are len 2-8).
__global__ __launch_bounds__(256, 4)
void fa2(const float* __restrict__ Q, const float* __restrict__ Kg,
         const int* __restrict__ kpl, const int* __restrict__ amask,
         float* __restrict__ Out, float* __restrict__ ws) {
  __shared__ __align__(16) ushort_t sm[SMEM2];
  const ushort_t* __restrict__ Vt = (const ushort_t*)(ws + WS2_VT);

  const int tid = threadIdx.x;
  const int lane = tid & 63;
  const int w = tid >> 6;               // 0..3
  const int qd = lane >> 4;
  const int nn = lane & 15;

  const int bx = blockIdx.x;            // 0..1247
  const int xcd = bx & 7;
  const int q = bx >> 3;                // 0..155
  const int b = xcd * 2 + (q & 1);      // 2 batches per XCD (L2 reuse)
  const int idx = q >> 1;               // 0..77
  const int flag = amask[0];

  int rt, c, nch;
  if (flag) {
    if (idx < 28)      { rt = 31 - (idx >> 2); c = idx & 3; }
    else if (idx < 52) { int i = idx - 28; int d = i / 3; rt = 24 - d; c = i - 3 * d; }
    else if (idx < 70) { int i = idx - 52; rt = 16 - (i >> 1); c = i & 1; }
    else               { rt = 77 - idx; c = 0; }
    nch = nch_of(rt);
  } else {
    if (idx >= 64) return;
    rt = idx >> 1; c = idx & 1; nch = 2;
  }
  const int ntf = flag ? (2 * rt + 2) : (SEQ_M / BC2);
  const int jt_lo = (ntf * c) / nch;
  const int jt_hi = (ntf * (c + 1)) / nch;

  const int mlimit = SEQ_M - kpl[b];
  const int i0w = rt * 64 + w * 16;
  const float c1 = 0.08838834764831845f * 1.4426950408889634f;  // scale*log2e

  // ---- Q fragments (A-layout, bf16) ----
  short8 qf[4];
  {
    const float* Qb = Q + ((size_t)b * SEQ_N + (size_t)(i0w + nn)) * DIM_D;
    union { short8 v; uint32_t u32[4]; } tq;
#pragma unroll
    for (int ks = 0; ks < 4; ++ks) {
      const float* pq = Qb + ks * 32 + qd * 8;
      float4 f0 = *(const float4*)pq, f1 = *(const float4*)(pq + 4);
      tq.u32[0] = bfpack(f0.x, f0.y);
      tq.u32[1] = bfpack(f0.z, f0.w);
      tq.u32[2] = bfpack(f1.x, f1.y);
      tq.u32[3] = bfpack(f1.z, f1.w);
      qf[ks] = tq.v;
    }
  }

  floatx4 o[8];
#pragma unroll
  for (int vt = 0; vt < 8; ++vt) o[vt] = (floatx4)0.0f;
  float m[4], l[4];
#pragma unroll
  for (int r = 0; r < 4; ++r) { m[r] = -3.0e38f; l[r] = 0.0f; }

  const size_t kgoff = (size_t)b * (SEQ_M * DIM_D);            // fp32 K
  const size_t vbatch = (size_t)b * ((size_t)DIM_V * SEQ_M);   // bf16 V^T

  // ---- K: global fp32 -> regs (T14 issue-early) -> convert -> swizzled LDS ----
  const int kr_row = tid >> 3;          // 0..31
  const int kcg    = tid & 7;           // 16-float col group
  float4 kr[4];
  auto kload = [&](int jt) {
    const float* p = Kg + kgoff + ((size_t)(jt * BC2 + kr_row) << 7) + kcg * 16;
    kr[0] = *(const float4*)p;       kr[1] = *(const float4*)(p + 4);
    kr[2] = *(const float4*)(p + 8); kr[3] = *(const float4*)(p + 12);
  };
  auto kwrite = [&](int buf, int jt) {
    uint4 w0, w1;
    w0.x = bfpack(kr[0].x, kr[0].y); w0.y = bfpack(kr[0].z, kr[0].w);
    w0.z = bfpack(kr[1].x, kr[1].y); w0.w = bfpack(kr[1].z, kr[1].w);
    w1.x = bfpack(kr[2].x, kr[2].y); w1.y = bfpack(kr[2].z, kr[2].w);
    w1.z = bfpack(kr[3].x, kr[3].y); w1.w = bfpack(kr[3].z, kr[3].w);
    if (jt * BC2 + kr_row >= mlimit) {
      w0 = make_uint4(0u, 0u, 0u, 0u);
      w1 = make_uint4(0u, 0u, 0u, 0u);
    }
    ushort_t* kb = &sm[K2OFF + buf * KELEMS + kr_row * 128];
    const int g0 = kcg * 2;
    *(uint4*)(kb + (((g0 + 0) ^ (kr_row & 7)) << 3)) = w0;
    *(uint4*)(kb + (((g0 + 1) ^ (kr_row & 7)) << 3)) = w1;
  };
  // V^T via async gload_lds; swizzle pre-applied on GLOBAL source (m173)
  auto stage_v = [&](int buf, int jt) {
    const int jb = jt * BC2;
#pragma unroll
    for (int i = 0; i < 2; ++i) {
      const int seg = w * 2 + i;                 // 0..7 (1KB segments)
      const int vrow = seg * 16 + (lane >> 2);   // V^T row (128 rows x 64B)
      const int colg = (lane & 3) ^ ((lane >> 4) & 3);  // == (lane&3)^((vrow>>2)&3)
      const ushort_t* src = Vt + vbatch + ((size_t)vrow << 11) + jb + colg * 8;
      stage16(src, &sm[V2OFF + buf * VELEMS + seg * 512], lane);
    }
  };

  kload(jt_lo);
  stage_v(0, jt_lo);
  kwrite(0, jt_lo);
  __syncthreads();

  const int len = jt_hi - jt_lo;
  const int swl = (nn & 7) << 3;          // K read swizzle (row&7 == nn&7)
  const int vsw = ((nn >> 2) & 3) << 3;   // V/P read swizzle ((row>>2)&3)
#pragma unroll 1
  for (int t = 0; t < len; ++t) {
    const int cur = t & 1;
    const int jt = jt_lo + t;
    const bool more = (t + 1) < len;
    const int jbase = jt * BC2;
    if (more) { kload(jt + 1); stage_v(cur ^ 1, jt + 1); }

    const int kb = K2OFF + cur * KELEMS;
    const int vb = V2OFF + cur * VELEMS;

    // ---- S = Q K^T (16 rows x 32 keys per wave) ----
    floatx4 sx[2];
#pragma unroll
    for (int ct = 0; ct < 2; ++ct) sx[ct] = (floatx4)0.0f;
    __builtin_amdgcn_s_setprio(1);
#pragma unroll
    for (int ks = 0; ks < 4; ++ks) {
#pragma unroll
      for (int ct = 0; ct < 2; ++ct) {
        short8 bf = *(const short8*)&sm[kb + (ct * 16 + nn) * 128
                                        + ((ks * 32 + qd * 8) ^ swl)];
        sx[ct] = __builtin_amdgcn_mfma_f32_16x16x32_bf16(qf[ks], bf, sx[ct], 0, 0, 0);
      }
    }
    __builtin_amdgcn_s_setprio(0);

    // ---- online softmax (16 rows/wave), defer-max (T13, THR=8) ----
    {
      const bool needmask = flag && (jbase + BC2 - 1 > i0w);
      if (needmask) {
#pragma unroll
        for (int ct = 0; ct < 2; ++ct) {
          const int jgl = jbase + ct * 16 + nn;
#pragma unroll
          for (int r = 0; r < 4; ++r) {
            float tv = sx[ct][r] * c1;
            sx[ct][r] = (jgl > i0w + qd * 4 + r) ? -3.0e38f : tv;
          }
        }
      } else {
#pragma unroll
        for (int ct = 0; ct < 2; ++ct)
#pragma unroll
          for (int r = 0; r < 4; ++r) sx[ct][r] *= c1;
      }
      float mr4[4];
#pragma unroll
      for (int r = 0; r < 4; ++r) mr4[r] = rowmax16(fmaxf(sx[0][r], sx[1][r]));
      bool need = false;
#pragma unroll
      for (int r = 0; r < 4; ++r) need = need || (mr4[r] > m[r] + 8.0f);
      if (__any(need ? 1 : 0)) {
#pragma unroll
        for (int r = 0; r < 4; ++r) {
          const float mn = fmaxf(m[r], mr4[r]);
          const float alpha = EXP2F(m[r] - mn);
          m[r] = mn;
          l[r] *= alpha;
#pragma unroll
          for (int vt = 0; vt < 8; ++vt) o[vt][r] *= alpha;
        }
      }
#pragma unroll
      for (int r = 0; r < 4; ++r) {
        const int prow = w * 16 + qd * 4 + r;
        float p0 = EXP2F(sx[0][r] - m[r]);
        float p1 = EXP2F(sx[1][r] - m[r]);
        l[r] += p0 + p1;
        sm[P2OFF + prow * 32 + ((0 * 16 + nn) ^ (qd << 3))] = f2bf(p0);
        sm[P2OFF + prow * 32 + ((1 * 16 + nn) ^ (qd << 3))] = f2bf(p1);
      }
    }

    // ---- O += P V (P rows wave-private; in-wave lgkm ordering suffices) ----
    __builtin_amdgcn_s_setprio(1);
    {
      short8 a = *(const short8*)&sm[P2OFF + (w * 16 + nn) * 32 + ((qd * 8) ^ vsw)];
#pragma unroll
      for (int vt = 0; vt < 8; ++vt) {
        short8 vbf = *(const short8*)&sm[vb + (vt * 16 + nn) * 32 + ((qd * 8) ^ vsw)];
        o[vt] = __builtin_amdgcn_mfma_f32_16x16x32_bf16(a, vbf, o[vt], 0, 0, 0);
      }
    }
    __builtin_amdgcn_s_setprio(0);

    if (more) kwrite(cur ^ 1, jt + 1);
    __syncthreads();
  }

  // ---- epilogue: unnormalized partial + (m,l); merge normalizes ----
#pragma unroll
  for (int r = 0; r < 4; ++r) l[r] = rowsum16(l[r]);

  const int cid = b * 78 + (flag ? (cbase_of(rt) + c) : (rt * 2 + c));
  if (c == 0) {
    float* Od = Out + ((size_t)b * SEQ_N + i0w) * DIM_V;
#pragma unroll
    for (int r = 0; r < 4; ++r) {
      const int row = qd * 4 + r;
#pragma unroll
      for (int vt = 0; vt < 8; ++vt)
        Od[(size_t)row * DIM_V + vt * 16 + nn] = o[vt][r];
    }
  } else {
    const int slot = flag ? (b * 46 + sbase_of(rt) + (c - 1)) : (b * 32 + rt);
    float* Od = ws + WS2_PO + (size_t)slot * (64 * DIM_V);
#pragma unroll
    for (int r = 0; r < 4; ++r) {
      const int row = w * 16 + qd * 4 + r;
#pragma unroll
      for (int vt = 0; vt < 8; ++vt)
        Od[(size_t)row * DIM_V + vt * 16 + nn] = o[vt][r];
    }
  }
  if (nn == 0) {
#pragma unroll
    for (int r = 0; r < 4; ++r) {
      const int row = w * 16 + qd * 4 + r;
      ws[WS2_M + cid * 64 + row] = m[r];
      ws[WS2_L + cid * 64 + row] = l[r];
    }
  }
}

// merge 1..4 chunks of every row (exp2-domain flash combine; chunk0 lives in Out)
__global__ __launch_bounds__(256)
void fa2_merge(float* __restrict__ Out, const float* __restrict__ ws,
               const int* __restrict__ amask) {
  const int w = threadIdx.x >> 6, lane = threadIdx.x & 63;
  const int rowid = blockIdx.x * 4 + w;        // 0..32767
  const int b = rowid >> 11;
  const int gr = rowid & 2047;
  const int rt = gr >> 6, rr = gr & 63;
  const int flag = amask[0];
  int nch, cb, sb;
  if (flag) { nch = nch_of(rt); cb = cbase_of(rt); sb = sbase_of(rt); }
  else      { nch = 2; cb = rt * 2; sb = 0; }
  const int cid0 = b * 78 + cb;

  float m0 = ws[WS2_M + (cid0 + 0) * 64 + rr];
  float l0 = ws[WS2_L + (cid0 + 0) * 64 + rr];
  float m1 = -3.0e38f, l1 = 0.0f, m2 = -3.0e38f, l2 = 0.0f, m3 = -3.0e38f, l3 = 0.0f;
  if (nch > 1) { m1 = ws[WS2_M + (cid0 + 1) * 64 + rr]; l1 = ws[WS2_L + (cid0 + 1) * 64 + rr]; }
  if (nch > 2) { m2 = ws[WS2_M + (cid0 + 2) * 64 + rr]; l2 = ws[WS2_L + (cid0 + 2) * 64 + rr]; }
  if (nch > 3) { m3 = ws[WS2_M + (cid0 + 3) * 64 + rr]; l3 = ws[WS2_L + (cid0 + 3) * 64 + rr]; }
  const float M = fmaxf(fmaxf(m0, m1), fmaxf(m2, m3));
  const float e0 = EXP2F(m0 - M), e1 = EXP2F(m1 - M);
  const float e2 = EXP2F(m2 - M), e3 = EXP2F(m3 - M);
  const float inv = 1.0f / (l0 * e0 + l1 * e1 + l2 * e2 + l3 * e3);

  float* O1 = Out + ((size_t)b * SEQ_N + gr) * DIM_V;
  float2 x = *(const float2*)(O1 + lane * 2);
  const float a0 = e0 * inv;
  float2 acc; acc.x = x.x * a0; acc.y = x.y * a0;
  const int slotb = flag ? (b * 46 + sb) : (b * 32 + rt);
  if (nch > 1) {
    const float* P = ws + WS2_PO + (size_t)(slotb + 0) * (64 * DIM_V) + rr * DIM_V;
    float2 y = *(const float2*)(P + lane * 2);
    const float a1 = e1 * inv; acc.x += y.x * a1; acc.y += y.y * a1;
  }
  if (nch > 2) {
    const float* P = ws + WS2_PO + (size_t)(slotb + 1) * (64 * DIM_V) + rr * DIM_V;
    float2 y = *(const float2*)(P + lane * 2);
    const float a2 = e2 * inv; acc.x += y.x * a2; acc.y += y.y * a2;
  }
  if (nch > 3) {
    const float* P = ws + WS2_PO + (size_t)(slotb + 2) * (64 * DIM_V) + rr * DIM_V;
    float2 y = *(const float2*)(P + lane * 2);
    const float a3 = e3 * inv; acc.x += y.x * a3; acc.y += y.y * a3;
  }
  *(float2*)(O1 + lane * 2) = acc;
}

// ======================= OLD PATH (verified fallback) =======================

#define KS_LD 136
#define VS_LD 72
#define PS_LD 72
#define KB(i) ((i) * 8704)
#define VB(i) (17408 + (i) * 9216)
#define P0 35840
#define SMEM_ELEMS 40448

#define WS_O_FLOATS (256 * 2 * 64 * 128)
#define WS_M_OFF    WS_O_FLOATS
#define WS_L_OFF    (WS_O_FLOATS + 32768)
#define WS_FLOATS   (WS_O_FLOATS + 65536)

__device__ __forceinline__ void process_chunk(
    const float* __restrict__ Q, const float* __restrict__ K,
    const float* __restrict__ Vg, float* __restrict__ Out,
    float* __restrict__ ws, ushort_t* __restrict__ smem,
    int b, int rt, int jt_lo, int jt_hi, int mlimit, int flag, int c, bool direct) {
  const int tid  = threadIdx.x;
  const int lane = tid & 63;
  const int w    = tid >> 6;
  const int qd   = lane >> 4;
  const int nn   = lane & 15;

  const float c1 = 0.08838834764831845f * 1.4426950408889634f;

  const int oct = tid & 15;
  const int j0  = (tid >> 4) * 4;
  const int hh  = nn >> 3;
  const int rb  = 8 * hh;

  const int i0w = rt * 64 + w * 16;
  const size_t koff = (size_t)b * SEQ_M * DIM_D;
  const size_t voff = (size_t)b * SEQ_M * DIM_V;

  short8 qf[4];
  {
    const float* Qb = Q + ((size_t)b * SEQ_N + (size_t)(i0w + nn)) * DIM_D;
    union { short8 v; uint32_t u32[4]; } t;
#pragma unroll
    for (int ks = 0; ks < 4; ++ks) {
      const float* p = Qb + ks * 32 + qd * 8;
      float4 f0 = *(const float4*)p, f1 = *(const float4*)(p + 4);
      t.u32[0] = bfpack(f0.x, f0.y);
      t.u32[1] = bfpack(f0.z, f0.w);
      t.u32[2] = bfpack(f1.x, f1.y);
      t.u32[3] = bfpack(f1.z, f1.w);
      qf[ks] = t.v;
    }
  }

  floatx4 o[8];
#pragma unroll
  for (int vt = 0; vt < 8; ++vt) o[vt] = (floatx4)0.0f;
  float m[4], l[4];
#pragma unroll
  for (int r = 0; r < 4; ++r) { m[r] = -3.0e38f; l[r] = 0.0f; }

  float4 kr[4][2], vr[4][2];

  auto stage_load = [&](int jt) {
    const int jbase = jt * BC;
#pragma unroll
    for (int r = 0; r < 4; ++r) {
      const float* kp = K  + koff + (size_t)(jbase + j0 + r) * DIM_D + oct * 8;
      kr[r][0] = *(const float4*)kp;  kr[r][1] = *(const float4*)(kp + 4);
      const float* vp = Vg + voff + (size_t)(jbase + j0 + r) * DIM_V + oct * 8;
      vr[r][0] = *(const float4*)vp;  vr[r][1] = *(const float4*)(vp + 4);
    }
  };

  auto stage_write = [&](int buf, int jt) {
    const int jbase = jt * BC;
    const int kb = KB(buf), vb = VB(buf);
#pragma unroll
    for (int r = 0; r < 4; ++r) {
      uint4 kw;
      kw.x = bfpack(kr[r][0].x, kr[r][0].y);
      kw.y = bfpack(kr[r][0].z, kr[r][0].w);
      kw.z = bfpack(kr[r][1].x, kr[r][1].y);
      kw.w = bfpack(kr[r][1].z, kr[r][1].w);
      if (jbase + j0 + r >= mlimit) kw = make_uint4(0u, 0u, 0u, 0u);
      *(uint4*)(smem + kb + (j0 + r) * KS_LD + oct * 8) = kw;
    }
    float vc[4][8];
#pragma unroll
    for (int r = 0; r < 4; ++r) {
      vc[r][0]=vr[r][0].x; vc[r][1]=vr[r][0].y; vc[r][2]=vr[r][0].z; vc[r][3]=vr[r][0].w;
      vc[r][4]=vr[r][1].x; vc[r][5]=vr[r][1].y; vc[r][6]=vr[r][1].z; vc[r][7]=vr[r][1].w;
    }
#pragma unroll
    for (int q = 0; q < 8; ++q) {
      const int p = 8 * oct + ((oct + q) & 7);
      uint2 dv;
      dv.x = bfpack(vc[0][q], vc[1][q]);
      dv.y = bfpack(vc[2][q], vc[3][q]);
      *(uint2*)(smem + vb + p * VS_LD + j0) = dv;
    }
  };

  stage_load(jt_lo);
  stage_write(0, jt_lo);
  __syncthreads();

  const int len = jt_hi - jt_lo;
#pragma unroll 1
  for (int t = 0; t < len; ++t) {
    const int jt = jt_lo + t;
    const int cur = t & 1;
    const bool more = (t + 1) < len;
    const int jbase = jt * BC;
    if (more) stage_load(jt + 1);

    const int kb = KB(cur), vb = VB(cur);

    floatx4 s[4];
#pragma unroll
    for (int ct = 0; ct < 4; ++ct) s[ct] = (floatx4)0.0f;
#pragma unroll
    for (int ks = 0; ks < 4; ++ks) {
#pragma unroll
      for (int ct = 0; ct < 4; ++ct) {
        short8 bf = *(const short8*)(smem + kb + (ct * 16 + nn) * KS_LD + ks * 32 + qd * 8);
        s[ct] = __builtin_amdgcn_mfma_f32_16x16x32_bf16(qf[ks], bf, s[ct], 0, 0, 0);
      }
    }

    {
      float tt[4][4];
      const bool needmask = flag && (jbase + BC - 1 > i0w);
#pragma unroll
      for (int ct = 0; ct < 4; ++ct)
#pragma unroll
        for (int r = 0; r < 4; ++r) {
          float tv = s[ct][r] * c1;
          if (needmask) {
            int jgl = jbase + ct * 16 + nn;
            int igl = i0w + qd * 4 + r;
            if (jgl > igl) tv = -3.0e38f;
          }
          tt[ct][r] = tv;
        }
#pragma unroll
      for (int r = 0; r < 4; ++r) {
        float mr = fmaxf(fmaxf(tt[0][r], tt[1][r]), fmaxf(tt[2][r], tt[3][r]));
        mr = rowmax16(mr);
        float mn = fmaxf(m[r], mr);
        float alpha = EXP2F(m[r] - mn);
        m[r] = mn;
        float ps = 0.0f;
#pragma unroll
        for (int ct = 0; ct < 4; ++ct) {
          float p = EXP2F(tt[ct][r] - mn);
          tt[ct][r] = p;
          ps += p;
        }
        l[r] = l[r] * alpha + ps;
#pragma unroll
        for (int vt = 0; vt < 8; ++vt) o[vt][r] *= alpha;
      }
#pragma unroll
      for (int ct = 0; ct < 4; ++ct)
#pragma unroll
        for (int r = 0; r < 4; ++r)
          smem[P0 + (w * 16 + qd * 4 + r) * PS_LD + ct * 16 + nn] = f2bf(tt[ct][r]);
    }

#pragma unroll
    for (int ks2 = 0; ks2 < 2; ++ks2) {
      short8 a = *(const short8*)(smem + P0 + (w * 16 + nn) * PS_LD + ks2 * 32 + qd * 8);
#pragma unroll
      for (int vt = 0; vt < 8; ++vt) {
        const int p = 16 * vt + rb + ((2 * vt + nn + hh) & 7);
        short8 vbf = *(const short8*)(smem + vb + p * VS_LD + ks2 * 32 + qd * 8);
        o[vt] = __builtin_amdgcn_mfma_f32_16x16x32_bf16(a, vbf, o[vt], 0, 0, 0);
      }
    }

    if (more) stage_write(cur ^ 1, jt + 1);
    __syncthreads();
  }

#pragma unroll
  for (int r = 0; r < 4; ++r) l[r] = rowsum16(l[r]);

  if (direct) {
    float* Ob = Out + ((size_t)b * SEQ_N + i0w) * DIM_V;
#pragma unroll
    for (int r = 0; r < 4; ++r) {
      float inv = 1.0f / l[r];
      int row = qd * 4 + r;
#pragma unroll
      for (int vt = 0; vt < 8; ++vt)
        Ob[(size_t)row * DIM_V + vt * 16 + nn] = o[vt][r] * inv;
    }
  } else {
    const int p = b * 16 + (rt - 16);
    const int slot = p * 2 + c;
    float* Op = ws + (size_t)slot * 64 * 128;
#pragma unroll
    for (int r = 0; r < 4; ++r) {
      int row = w * 16 + qd * 4 + r;
#pragma unroll
      for (int vt = 0; vt < 8; ++vt)
        Op[(size_t)row * 128 + vt * 16 + nn] = o[vt][r];
    }
    if (nn == 0) {
#pragma unroll
      for (int r = 0; r < 4; ++r) {
        int row = w * 16 + qd * 4 + r;
        ws[WS_M_OFF + slot * 64 + row] = m[r];
        ws[WS_L_OFF + slot * 64 + row] = l[r];
      }
    }
  }
}

__global__ __launch_bounds__(256, 2)
void fa_chunk(const float* __restrict__ Q, const float* __restrict__ K,
              const float* __restrict__ Vg, const int* __restrict__ kpl,
              const int* __restrict__ amask, float* __restrict__ Out,
              float* __restrict__ ws) {
  __shared__ __align__(16) ushort_t smem[SMEM_ELEMS];
  const int bx = blockIdx.x;
  const int b  = bx & 15;
  const int u  = bx >> 4;
  int rt, c;
  if (u < 16)      { rt = 16 + u; c = 0; }
  else if (u < 32) { rt = 47 - u; c = 1; }
  else             { rt = 47 - u; c = 0; }
  const int flag   = amask[0];
  const int mlimit = SEQ_M - kpl[b];
  const int ntiles = flag ? (rt + 1) : (SEQ_M / BC);
  const int jt_lo  = (c == 1) ? 16 : 0;
  const int jt_hi  = (c == 0 && rt >= 16) ? 16 : ntiles;
  process_chunk(Q, K, Vg, Out, ws, smem, b, rt, jt_lo, jt_hi, mlimit, flag, c, rt < 16);
}

__global__ __launch_bounds__(256)
void fa_merge(const float* __restrict__ ws, float* __restrict__ Out) {
  const int w = threadIdx.x >> 6, lane = threadIdx.x & 63;
  const int rowid = blockIdx.x * 4 + w;
  const int p = rowid >> 6, rr = rowid & 63;
  const int b = p >> 4, rt = 16 + (p & 15);
  float m1 = ws[WS_M_OFF + (p * 2 + 0) * 64 + rr];
  float l1 = ws[WS_L_OFF + (p * 2 + 0) * 64 + rr];
  float m2 = ws[WS_M_OFF + (p * 2 + 1) * 64 + rr];
  float l2 = ws[WS_L_OFF + (p * 2 + 1) * 64 + rr];
  float M  = fmaxf(m1, m2);
  float a1 = EXP2F(m1 - M), a2 = EXP2F(m2 - M);
  float inv = 1.0f / (l1 * a1 + l2 * a2);
  const float* O1 = ws + ((size_t)(p * 2 + 0) * 64 + rr) * 128;
  const float* O2 = ws + ((size_t)(p * 2 + 1) * 64 + rr) * 128;
  float2 x1 = *(const float2*)(O1 + lane * 2);
  float2 x2 = *(const float2*)(O2 + lane * 2);
  float2 r;
  r.x = (x1.x * a1 + x2.x * a2) * inv;
  r.y = (x1.y * a1 + x2.y * a2) * inv;
  *(float2*)(Out + ((size_t)b * SEQ_N + rt * 64 + rr) * 128 + lane * 2) = r;
}

__global__ __launch_bounds__(256, 2)
void fa_paired(const float* __restrict__ Q, const float* __restrict__ K,
               const float* __restrict__ Vg, const int* __restrict__ kpl,
               const int* __restrict__ amask, float* __restrict__ Out) {
  __shared__ __align__(16) ushort_t smem[SMEM_ELEMS];
  const int bx = blockIdx.x;
  const int b  = bx & 15;
  const int pp = bx >> 4;
  const int flag   = amask[0];
  const int mlimit = SEQ_M - kpl[b];
#pragma unroll 1
  for (int ph = 0; ph < 2; ++ph) {
    const int rt = ph ? (31 - pp) : pp;
    const int ntiles = flag ? (rt + 1) : (SEQ_M / BC);
    process_chunk(Q, K, Vg, Out, nullptr, smem, b, rt, 0, ntiles, mlimit, flag, 0, true);
  }
}

extern "C" void kernel_launch(void* const* d_in, const int* in_sizes, int n_in,
                              void* d_out, int out_size, void* d_ws, size_t ws_size,
                              hipStream_t stream) {
  const float* Q   = (const float*)d_in[0];
  const float* K   = (const float*)d_in[1];
  const float* V   = (const float*)d_in[2];
  const int* kpl   = (const int*)d_in[3];
  const int* amask = (const int*)d_in[4];
  float* O         = (float*)d_out;
  float* ws        = (float*)d_ws;

  if (ws_size >= (size_t)WS2_FLOATS * 4) {
    hipLaunchKernelGGL(prep2, dim3(1024), dim3(256), 0, stream, V, ws);
    hipLaunchKernelGGL(fa2, dim3(1248), dim3(256), 0, stream, Q, K, kpl, amask, O, ws);
    hipLaunchKernelGGL(fa2_merge, dim3(8192), dim3(256), 0, stream, O, ws, amask);
  } else if (ws_size >= (size_t)WS_FLOATS * 4) {
    hipLaunchKernelGGL(fa_chunk, dim3(768), dim3(256), 0, stream, Q, K, V, kpl, amask, O, ws);
    hipLaunchKernelGGL(fa_merge, dim3(4096), dim3(256), 0, stream, ws, O);
  } else {
    hipLaunchKernelGGL(fa_paired, dim3(256), dim3(256), 0, stream, Q, K, V, kpl, amask, O);
  }
}

// Round 5
// 153.949 us; speedup vs baseline: 1.0632x; 1.0632x over previous
//
#include <hip/hip_runtime.h>
#include <stdint.h>

typedef unsigned short ushort_t;
typedef __attribute__((ext_vector_type(8))) short short8;   // 8 x bf16 (4 VGPRs)
typedef __attribute__((ext_vector_type(4))) float floatx4;  // MFMA accum

#define SEQ_N 2048
#define SEQ_M 2048
#define DIM_D 128
#define DIM_V 128
#define BC 64    // keys per tile (OLD path)
#define BC2 32   // keys per tile (NEW path)

// ======================= common helpers =======================

#if __has_builtin(__builtin_amdgcn_exp2f)
#define EXP2F(x) __builtin_amdgcn_exp2f(x)
#else
#define EXP2F(x) exp2f(x)
#endif

template <int CTRL>
__device__ __forceinline__ float dpp_f(float x) {
  int xi = __builtin_bit_cast(int, x);
  int yi = __builtin_amdgcn_update_dpp(xi, xi, CTRL, 0xf, 0xf, false);
  return __builtin_bit_cast(float, yi);
}
__device__ __forceinline__ float rowmax16(float x) {
  x = fmaxf(x, dpp_f<0x128>(x));
  x = fmaxf(x, dpp_f<0x124>(x));
  x = fmaxf(x, dpp_f<0x122>(x));
  x = fmaxf(x, dpp_f<0x121>(x));
  return x;
}
__device__ __forceinline__ float rowsum16(float x) {
  x += dpp_f<0x128>(x);
  x += dpp_f<0x124>(x);
  x += dpp_f<0x122>(x);
  x += dpp_f<0x121>(x);
  return x;
}

__device__ __forceinline__ ushort_t f2bf(float f) {
  uint32_t u = __builtin_bit_cast(uint32_t, f);
  return (ushort_t)((u + 0x8000u) >> 16);
}
// pack two fp32 -> bf16 pair in ONE v_perm (3 VALU total, bit-identical to f2bf pair)
__device__ __forceinline__ uint32_t bfpack(float lo, float hi) {
  uint32_t a = __builtin_bit_cast(uint32_t, lo) + 0x8000u;
  uint32_t b = __builtin_bit_cast(uint32_t, hi) + 0x8000u;
  return __builtin_amdgcn_perm(b, a, 0x07060302u);  // {b[31:16], a[31:16]}
}

// ======================= NEW PATH =======================
// BM=64 rows/block, BC2=32 keys/tile, 256 threads (4 waves x 16 rows).
// LDS (ushort): K 2x[32][128] (8KB ea), Vt 2x[128][32] (8KB ea), P [64][32] (4KB)
// = 36864 B -> 4 blocks/CU. Tile loop is the proven round-3 body (Kb/Vt bf16
// prep + global_load_lds staging). Schedule is a runtime MODE from ws_size:
//   mode0 (ws>=34,078,720 B): nch=2 for all rows (proven 56.8us schedule)
//   mode1 (ws>=35,143,680 B): chunks capped at 22 tiles (nch<=3), 1056 blocks
//   mode2 (ws>=41,533,440 B): chunks capped at 17 tiles (nch<=4), 1248 blocks
#define K2OFF 0
#define V2OFF 8192
#define P2OFF 16384
#define SMEM2 18432
#define KELEMS 4096
#define VELEMS 4096

// ws layout (floats): Kb bf16 [16][2048][128], Vt bf16 [16][128][2048],
// PO fp32 partial-O slots (64x128 each), then M/L (per-mode offsets).
#define WS2_KB 0
#define WS2_VT 2097152
#define WS2_PO 4194304
// mode0: PO 512 slots; M @ 8388608, L @ 8454144; end 8519680  (34,078,720 B)
// mode1: PO 544 slots; M @ 8650752, L @ 8718336; end 8785920  (35,143,680 B)
// mode2: PO 736 slots; M @ 10223616, L @ 10303488; end 10383360 (41,533,440 B)

// async 16B global->LDS; lds_base must be wave-uniform (HW adds lane*16)
__device__ __forceinline__ void stage16(const ushort_t* src, ushort_t* lds_base, int lane) {
#if __has_builtin(__builtin_amdgcn_global_load_lds)
  __builtin_amdgcn_global_load_lds(
      (const __attribute__((address_space(1))) void*)src,
      (__attribute__((address_space(3))) void*)lds_base, 16, 0, 0);
#else
  *(uint4*)(lds_base + lane * 8) = *(const uint4*)src;
#endif
}

// prep: K -> bf16 (+ padding mask), V -> bf16 transposed [b][v][m]
__global__ __launch_bounds__(256)
void prep2(const float* __restrict__ K, const float* __restrict__ Vg,
           const int* __restrict__ kpl, float* __restrict__ ws) {
  __shared__ __align__(16) ushort_t lt[64][72];
  ushort_t* Kb = (ushort_t*)(ws + WS2_KB);
  ushort_t* Vt = (ushort_t*)(ws + WS2_VT);
  const int g = blockIdx.x, tid = threadIdx.x;
  if (g < 2048) {
    const size_t e = (size_t)g * 2048 + (size_t)tid * 8;
    const int row = (int)(e >> 7);
    const int b = row >> 11, mm = row & 2047;
    const int mlimit = SEQ_M - kpl[b];
    uint4 kw = make_uint4(0u, 0u, 0u, 0u);
    if (mm < mlimit) {
      const float* p = K + e;
      float4 f0 = *(const float4*)p, f1 = *(const float4*)(p + 4);
      kw.x = bfpack(f0.x, f0.y); kw.y = bfpack(f0.z, f0.w);
      kw.z = bfpack(f1.x, f1.y); kw.w = bfpack(f1.z, f1.w);
    }
    *(uint4*)(Kb + e) = kw;
  } else {
    const int g2 = g - 2048;
    const int b = g2 >> 6;
    const int mt = (g2 & 63) >> 1;
    const int vh = (g2 & 1) * 64;
    const int mrow = tid >> 2, v0 = (tid & 3) * 16;
    const float* p = Vg + ((size_t)b * SEQ_M + (size_t)(mt * 64 + mrow)) * DIM_V + vh + v0;
    float4 f0 = *(const float4*)p, f1 = *(const float4*)(p + 4);
    float4 f2 = *(const float4*)(p + 8), f3 = *(const float4*)(p + 12);
    lt[v0 +  0][mrow] = f2bf(f0.x); lt[v0 +  1][mrow] = f2bf(f0.y);
    lt[v0 +  2][mrow] = f2bf(f0.z); lt[v0 +  3][mrow] = f2bf(f0.w);
    lt[v0 +  4][mrow] = f2bf(f1.x); lt[v0 +  5][mrow] = f2bf(f1.y);
    lt[v0 +  6][mrow] = f2bf(f1.z); lt[v0 +  7][mrow] = f2bf(f1.w);
    lt[v0 +  8][mrow] = f2bf(f2.x); lt[v0 +  9][mrow] = f2bf(f2.y);
    lt[v0 + 10][mrow] = f2bf(f2.z); lt[v0 + 11][mrow] = f2bf(f2.w);
    lt[v0 + 12][mrow] = f2bf(f3.x); lt[v0 + 13][mrow] = f2bf(f3.y);
    lt[v0 + 14][mrow] = f2bf(f3.z); lt[v0 + 15][mrow] = f2bf(f3.w);
    __syncthreads();
    const int v = tid >> 2, mo = (tid & 3) * 16;
    ushort_t* dst = Vt + ((size_t)(b * DIM_V + vh + v) * SEQ_M) + mt * 64 + mo;
    *(uint4*)(dst + 0) = *(const uint4*)&lt[v][mo];
    *(uint4*)(dst + 8) = *(const uint4*)&lt[v][mo + 8];
  }
}

// per-mode chunk tables (causal)
__device__ __forceinline__ int nch_m1(int rt) { return (rt <= 7) ? 1 : ((rt <= 21) ? 2 : 3); }
__device__ __forceinline__ int cb_m1(int rt) {
  return (rt <= 7) ? rt : ((rt <= 21) ? (8 + 2 * (rt - 8)) : (36 + 3 * (rt - 22)));
}
__device__ __forceinline__ int sb_m1(int rt) {
  return (rt <= 7) ? 0 : ((rt <= 21) ? (rt - 8) : (14 + 2 * (rt - 22)));
}
__device__ __forceinline__ int nch_m2(int rt) {
  return (rt <= 7) ? 1 : ((rt <= 16) ? 2 : ((rt <= 24) ? 3 : 4));
}
__device__ __forceinline__ int cb_m2(int rt) {
  return (rt <= 7) ? rt
       : ((rt <= 16) ? (8 + 2 * (rt - 8))
       : ((rt <= 24) ? (26 + 3 * (rt - 17)) : (50 + 4 * (rt - 25))));
}
__device__ __forceinline__ int sb_m2(int rt) {
  return (rt <= 7) ? 0
       : ((rt <= 16) ? (rt - 8)
       : ((rt <= 24) ? (9 + 2 * (rt - 17)) : (25 + 3 * (rt - 25))));
}

__global__ __launch_bounds__(256, 4)
void fa2(const float* __restrict__ Q, const int* __restrict__ amask,
         float* __restrict__ Out, float* __restrict__ ws,
         float* __restrict__ PO, float* __restrict__ MP, float* __restrict__ LP,
         int mode) {
  __shared__ __align__(16) ushort_t sm[SMEM2];
  const ushort_t* __restrict__ Kb = (const ushort_t*)(ws + WS2_KB);
  const ushort_t* __restrict__ Vt = (const ushort_t*)(ws + WS2_VT);

  const int tid = threadIdx.x;
  const int lane = tid & 63;
  const int w = tid >> 6;               // 0..3
  const int qd = lane >> 4;
  const int nn = lane & 15;

  const int bx = blockIdx.x;
  const int xcd = bx & 7;
  const int q = bx >> 3;
  const int flag = amask[0];

  int b, rt, c, nch;
  if (mode == 0) {
    // proven round-3 s-map: 1024 blocks, nch=2 for all rows
    const int s = q >> 5, v5 = q & 31, pz = v5 & 1, j = v5 >> 1;
    b = xcd * 2 + pz;
    const int jj = pz ? (15 - j) : j;
    if (s == 0)      { rt = jj;      c = 0; }
    else if (s == 1) { rt = 31 - jj; c = 0; }
    else if (s == 2) { rt = 16 + jj; c = 1; }
    else             { rt = 15 - jj; c = 1; }
    nch = 2;
  } else {
    b = xcd * 2 + (q & 1);
    const int idx = q >> 1;
    if (flag) {
      if (mode == 1) {
        if (idx < 30)      { const int d = idx / 3; rt = 31 - d; c = idx - 3 * d; }
        else if (idx < 58) { const int i = idx - 30; rt = 21 - (i >> 1); c = i & 1; }
        else               { rt = 65 - idx; c = 0; }
        nch = nch_m1(rt);
      } else {
        if (idx < 28)      { rt = 31 - (idx >> 2); c = idx & 3; }
        else if (idx < 52) { const int i = idx - 28; const int d = i / 3; rt = 24 - d; c = i - 3 * d; }
        else if (idx < 70) { const int i = idx - 52; rt = 16 - (i >> 1); c = i & 1; }
        else               { rt = 77 - idx; c = 0; }
        nch = nch_m2(rt);
      }
    } else {
      if (idx >= 64) return;
      rt = idx >> 1; c = idx & 1; nch = 2;
    }
  }

  const int ntf = flag ? (2 * rt + 2) : (SEQ_M / BC2);
  const int jt_lo = (ntf * c) / nch;
  const int jt_hi = (ntf * (c + 1)) / nch;

  const int i0w = rt * 64 + w * 16;
  const float c1 = 0.08838834764831845f * 1.4426950408889634f;  // scale*log2e

  // ---- Q fragments (A-layout, bf16) ----
  short8 qf[4];
  {
    const float* Qb = Q + ((size_t)b * SEQ_N + (size_t)(i0w + nn)) * DIM_D;
    union { short8 v; uint32_t u32[4]; } tq;
#pragma unroll
    for (int ks = 0; ks < 4; ++ks) {
      const float* pq = Qb + ks * 32 + qd * 8;
      float4 f0 = *(const float4*)pq, f1 = *(const float4*)(pq + 4);
      tq.u32[0] = bfpack(f0.x, f0.y);
      tq.u32[1] = bfpack(f0.z, f0.w);
      tq.u32[2] = bfpack(f1.x, f1.y);
      tq.u32[3] = bfpack(f1.z, f1.w);
      qf[ks] = tq.v;
    }
  }

  floatx4 o[8];
#pragma unroll
  for (int vt = 0; vt < 8; ++vt) o[vt] = (floatx4)0.0f;
  float m[4], l[4];
#pragma unroll
  for (int r = 0; r < 4; ++r) { m[r] = -3.0e38f; l[r] = 0.0f; }

  const size_t kbatch = (size_t)b * (SEQ_M * DIM_D);
  const size_t vbatch = (size_t)b * ((size_t)DIM_V * SEQ_M);

  // async stage of one K tile (32x128) + one V^T tile (128x32) into buf.
  // LDS linear; swizzles applied on the GLOBAL source (m173): K granule
  // ^= (row&7), V granule (of 4 per 64B row) ^= (row>>2)&3.
  auto stage = [&](int buf, int jt) {
    const int jb = jt * BC2;
#pragma unroll
    for (int i = 0; i < 2; ++i) {
      const int seg = w * 2 + i;                 // 0..7 (1KB segments)
      {
        const int rrow = seg * 4 + (lane >> 4);  // K row in tile (32 rows x 256B)
        const int col  = ((lane & 15) * 8) ^ ((rrow & 7) << 3);
        const ushort_t* src = Kb + kbatch + ((size_t)(jb + rrow) << 7) + col;
        stage16(src, &sm[K2OFF + buf * KELEMS + seg * 512], lane);
      }
      {
        const int vrow = seg * 16 + (lane >> 2); // V^T row (128 rows x 64B)
        const int colg = (lane & 3) ^ ((lane >> 4) & 3);  // == (lane&3)^((vrow>>2)&3)
        const ushort_t* src = Vt + vbatch + ((size_t)vrow << 11) + jb + colg * 8;
        stage16(src, &sm[V2OFF + buf * VELEMS + seg * 512], lane);
      }
    }
  };

  stage(0, jt_lo);
  __syncthreads();

  const int len = jt_hi - jt_lo;
  const int swl = (nn & 7) << 3;          // K read swizzle (row&7 == nn&7)
  const int vsw = ((nn >> 2) & 3) << 3;   // V/P read swizzle ((row>>2)&3)
#pragma unroll 1
  for (int t = 0; t < len; ++t) {
    const int cur = t & 1;
    const int jbase = (jt_lo + t) * BC2;
    if (t + 1 < len) stage(cur ^ 1, jt_lo + t + 1);

    const int kb = K2OFF + cur * KELEMS;
    const int vb = V2OFF + cur * VELEMS;

    // ---- S = Q K^T (16 rows x 32 keys per wave) ----
    floatx4 sx[2];
#pragma unroll
    for (int ct = 0; ct < 2; ++ct) sx[ct] = (floatx4)0.0f;
    __builtin_amdgcn_s_setprio(1);
#pragma unroll
    for (int ks = 0; ks < 4; ++ks) {
#pragma unroll
      for (int ct = 0; ct < 2; ++ct) {
        short8 bf = *(const short8*)&sm[kb + (ct * 16 + nn) * 128
                                        + ((ks * 32 + qd * 8) ^ swl)];
        sx[ct] = __builtin_amdgcn_mfma_f32_16x16x32_bf16(qf[ks], bf, sx[ct], 0, 0, 0);
      }
    }
    __builtin_amdgcn_s_setprio(0);

    // ---- online softmax (16 rows/wave), defer-max (T13, THR=8) ----
    {
      const bool needmask = flag && (jbase + BC2 - 1 > i0w);
      if (needmask) {
#pragma unroll
        for (int ct = 0; ct < 2; ++ct) {
          const int jgl = jbase + ct * 16 + nn;
#pragma unroll
          for (int r = 0; r < 4; ++r) {
            float tv = sx[ct][r] * c1;
            sx[ct][r] = (jgl > i0w + qd * 4 + r) ? -3.0e38f : tv;
          }
        }
      } else {
#pragma unroll
        for (int ct = 0; ct < 2; ++ct)
#pragma unroll
          for (int r = 0; r < 4; ++r) sx[ct][r] *= c1;
      }
      float mr4[4];
#pragma unroll
      for (int r = 0; r < 4; ++r) mr4[r] = rowmax16(fmaxf(sx[0][r], sx[1][r]));
      bool need = false;
#pragma unroll
      for (int r = 0; r < 4; ++r) need = need || (mr4[r] > m[r] + 8.0f);
      if (__any(need ? 1 : 0)) {
#pragma unroll
        for (int r = 0; r < 4; ++r) {
          const float mn = fmaxf(m[r], mr4[r]);
          const float alpha = EXP2F(m[r] - mn);
          m[r] = mn;
          l[r] *= alpha;
#pragma unroll
          for (int vt = 0; vt < 8; ++vt) o[vt][r] *= alpha;
        }
      }
#pragma unroll
      for (int r = 0; r < 4; ++r) {
        const int prow = w * 16 + qd * 4 + r;
        float p0 = EXP2F(sx[0][r] - m[r]);
        float p1 = EXP2F(sx[1][r] - m[r]);
        l[r] += p0 + p1;
        sm[P2OFF + prow * 32 + ((0 * 16 + nn) ^ (qd << 3))] = f2bf(p0);
        sm[P2OFF + prow * 32 + ((1 * 16 + nn) ^ (qd << 3))] = f2bf(p1);
      }
    }

    // ---- O += P V (P rows wave-private; in-wave lgkm ordering suffices) ----
    __builtin_amdgcn_s_setprio(1);
    {
      short8 a = *(const short8*)&sm[P2OFF + (w * 16 + nn) * 32 + ((qd * 8) ^ vsw)];
#pragma unroll
      for (int vt = 0; vt < 8; ++vt) {
        short8 vbf = *(const short8*)&sm[vb + (vt * 16 + nn) * 32 + ((qd * 8) ^ vsw)];
        o[vt] = __builtin_amdgcn_mfma_f32_16x16x32_bf16(a, vbf, o[vt], 0, 0, 0);
      }
    }
    __builtin_amdgcn_s_setprio(0);

    __syncthreads();
  }

  // ---- epilogue: unnormalized partial + (m,l); merge normalizes ----
#pragma unroll
  for (int r = 0; r < 4; ++r) l[r] = rowsum16(l[r]);

  int cid, slotb;
  if (mode == 0)      { cid = (b * 32 + rt) * 2 + c; slotb = b * 32 + rt; }
  else if (mode == 1) { cid = b * 66 + (flag ? cb_m1(rt) : rt * 2) + c;
                        slotb = b * 34 + (flag ? sb_m1(rt) : rt); }
  else                { cid = b * 78 + (flag ? cb_m2(rt) : rt * 2) + c;
                        slotb = b * 46 + (flag ? sb_m2(rt) : rt); }

  if (c == 0) {
    float* Od = Out + ((size_t)b * SEQ_N + i0w) * DIM_V;
#pragma unroll
    for (int r = 0; r < 4; ++r) {
      const int row = qd * 4 + r;
#pragma unroll
      for (int vt = 0; vt < 8; ++vt)
        Od[(size_t)row * DIM_V + vt * 16 + nn] = o[vt][r];
    }
  } else {
    float* Od = PO + (size_t)(slotb + c - 1) * (64 * DIM_V);
#pragma unroll
    for (int r = 0; r < 4; ++r) {
      const int row = w * 16 + qd * 4 + r;
#pragma unroll
      for (int vt = 0; vt < 8; ++vt)
        Od[(size_t)row * DIM_V + vt * 16 + nn] = o[vt][r];
    }
  }
  if (nn == 0) {
#pragma unroll
    for (int r = 0; r < 4; ++r) {
      const int row = w * 16 + qd * 4 + r;
      MP[cid * 64 + row] = m[r];
      LP[cid * 64 + row] = l[r];
    }
  }
}

// merge 1..4 chunks of every row (exp2-domain flash combine; chunk0 lives in Out)
__global__ __launch_bounds__(256)
void fa2_merge(float* __restrict__ Out, const float* __restrict__ PO,
               const float* __restrict__ MP, const float* __restrict__ LP,
               const int* __restrict__ amask, int mode) {
  const int w = threadIdx.x >> 6, lane = threadIdx.x & 63;
  const int rowid = blockIdx.x * 4 + w;        // 0..32767
  const int b = rowid >> 11;
  const int gr = rowid & 2047;
  const int rt = gr >> 6, rr = gr & 63;
  const int flag = amask[0];

  int nch, cid0, slotb;
  if (mode == 0)      { nch = 2; cid0 = (b * 32 + rt) * 2; slotb = b * 32 + rt; }
  else if (mode == 1) {
    if (flag) { nch = nch_m1(rt); cid0 = b * 66 + cb_m1(rt); slotb = b * 34 + sb_m1(rt); }
    else      { nch = 2; cid0 = b * 66 + rt * 2; slotb = b * 34 + rt; }
  } else {
    if (flag) { nch = nch_m2(rt); cid0 = b * 78 + cb_m2(rt); slotb = b * 46 + sb_m2(rt); }
    else      { nch = 2; cid0 = b * 78 + rt * 2; slotb = b * 46 + rt; }
  }

  float m0 = MP[(cid0 + 0) * 64 + rr];
  float l0 = LP[(cid0 + 0) * 64 + rr];
  float m1 = -3.0e38f, l1 = 0.0f, m2 = -3.0e38f, l2 = 0.0f, m3 = -3.0e38f, l3 = 0.0f;
  if (nch > 1) { m1 = MP[(cid0 + 1) * 64 + rr]; l1 = LP[(cid0 + 1) * 64 + rr]; }
  if (nch > 2) { m2 = MP[(cid0 + 2) * 64 + rr]; l2 = LP[(cid0 + 2) * 64 + rr]; }
  if (nch > 3) { m3 = MP[(cid0 + 3) * 64 + rr]; l3 = LP[(cid0 + 3) * 64 + rr]; }
  const float M = fmaxf(fmaxf(m0, m1), fmaxf(m2, m3));
  const float e0 = EXP2F(m0 - M), e1 = EXP2F(m1 - M);
  const float e2 = EXP2F(m2 - M), e3 = EXP2F(m3 - M);
  const float inv = 1.0f / (l0 * e0 + l1 * e1 + l2 * e2 + l3 * e3);

  float* O1 = Out + ((size_t)b * SEQ_N + gr) * DIM_V;
  float2 x = *(const float2*)(O1 + lane * 2);
  const float a0 = e0 * inv;
  float2 acc; acc.x = x.x * a0; acc.y = x.y * a0;
  if (nch > 1) {
    const float* P = PO + (size_t)(slotb + 0) * (64 * DIM_V) + rr * DIM_V;
    float2 y = *(const float2*)(P + lane * 2);
    const float a1 = e1 * inv; acc.x += y.x * a1; acc.y += y.y * a1;
  }
  if (nch > 2) {
    const float* P = PO + (size_t)(slotb + 1) * (64 * DIM_V) + rr * DIM_V;
    float2 y = *(const float2*)(P + lane * 2);
    const float a2 = e2 * inv; acc.x += y.x * a2; acc.y += y.y * a2;
  }
  if (nch > 3) {
    const float* P = PO + (size_t)(slotb + 2) * (64 * DIM_V) + rr * DIM_V;
    float2 y = *(const float2*)(P + lane * 2);
    const float a3 = e3 * inv; acc.x += y.x * a3; acc.y += y.y * a3;
  }
  *(float2*)(O1 + lane * 2) = acc;
}

// ======================= OLD PATH (verified fallback) =======================

#define KS_LD 136
#define VS_LD 72
#define PS_LD 72
#define KB(i) ((i) * 8704)
#define VB(i) (17408 + (i) * 9216)
#define P0 35840
#define SMEM_ELEMS 40448

#define WS_O_FLOATS (256 * 2 * 64 * 128)
#define WS_M_OFF    WS_O_FLOATS
#define WS_L_OFF    (WS_O_FLOATS + 32768)
#define WS_FLOATS   (WS_O_FLOATS + 65536)

__device__ __forceinline__ void process_chunk(
    const float* __restrict__ Q, const float* __restrict__ K,
    const float* __restrict__ Vg, float* __restrict__ Out,
    float* __restrict__ ws, ushort_t* __restrict__ smem,
    int b, int rt, int jt_lo, int jt_hi, int mlimit, int flag, int c, bool direct) {
  const int tid  = threadIdx.x;
  const int lane = tid & 63;
  const int w    = tid >> 6;
  const int qd   = lane >> 4;
  const int nn   = lane & 15;

  const float c1 = 0.08838834764831845f * 1.4426950408889634f;

  const int oct = tid & 15;
  const int j0  = (tid >> 4) * 4;
  const int hh  = nn >> 3;
  const int rb  = 8 * hh;

  const int i0w = rt * 64 + w * 16;
  const size_t koff = (size_t)b * SEQ_M * DIM_D;
  const size_t voff = (size_t)b * SEQ_M * DIM_V;

  short8 qf[4];
  {
    const float* Qb = Q + ((size_t)b * SEQ_N + (size_t)(i0w + nn)) * DIM_D;
    union { short8 v; uint32_t u32[4]; } t;
#pragma unroll
    for (int ks = 0; ks < 4; ++ks) {
      const float* p = Qb + ks * 32 + qd * 8;
      float4 f0 = *(const float4*)p, f1 = *(const float4*)(p + 4);
      t.u32[0] = bfpack(f0.x, f0.y);
      t.u32[1] = bfpack(f0.z, f0.w);
      t.u32[2] = bfpack(f1.x, f1.y);
      t.u32[3] = bfpack(f1.z, f1.w);
      qf[ks] = t.v;
    }
  }

  floatx4 o[8];
#pragma unroll
  for (int vt = 0; vt < 8; ++vt) o[vt] = (floatx4)0.0f;
  float m[4], l[4];
#pragma unroll
  for (int r = 0; r < 4; ++r) { m[r] = -3.0e38f; l[r] = 0.0f; }

  float4 kr[4][2], vr[4][2];

  auto stage_load = [&](int jt) {
    const int jbase = jt * BC;
#pragma unroll
    for (int r = 0; r < 4; ++r) {
      const float* kp = K  + koff + (size_t)(jbase + j0 + r) * DIM_D + oct * 8;
      kr[r][0] = *(const float4*)kp;  kr[r][1] = *(const float4*)(kp + 4);
      const float* vp = Vg + voff + (size_t)(jbase + j0 + r) * DIM_V + oct * 8;
      vr[r][0] = *(const float4*)vp;  vr[r][1] = *(const float4*)(vp + 4);
    }
  };

  auto stage_write = [&](int buf, int jt) {
    const int jbase = jt * BC;
    const int kb = KB(buf), vb = VB(buf);
#pragma unroll
    for (int r = 0; r < 4; ++r) {
      uint4 kw;
      kw.x = bfpack(kr[r][0].x, kr[r][0].y);
      kw.y = bfpack(kr[r][0].z, kr[r][0].w);
      kw.z = bfpack(kr[r][1].x, kr[r][1].y);
      kw.w = bfpack(kr[r][1].z, kr[r][1].w);
      if (jbase + j0 + r >= mlimit) kw = make_uint4(0u, 0u, 0u, 0u);
      *(uint4*)(smem + kb + (j0 + r) * KS_LD + oct * 8) = kw;
    }
    float vc[4][8];
#pragma unroll
    for (int r = 0; r < 4; ++r) {
      vc[r][0]=vr[r][0].x; vc[r][1]=vr[r][0].y; vc[r][2]=vr[r][0].z; vc[r][3]=vr[r][0].w;
      vc[r][4]=vr[r][1].x; vc[r][5]=vr[r][1].y; vc[r][6]=vr[r][1].z; vc[r][7]=vr[r][1].w;
    }
#pragma unroll
    for (int q = 0; q < 8; ++q) {
      const int p = 8 * oct + ((oct + q) & 7);
      uint2 dv;
      dv.x = bfpack(vc[0][q], vc[1][q]);
      dv.y = bfpack(vc[2][q], vc[3][q]);
      *(uint2*)(smem + vb + p * VS_LD + j0) = dv;
    }
  };

  stage_load(jt_lo);
  stage_write(0, jt_lo);
  __syncthreads();

  const int len = jt_hi - jt_lo;
#pragma unroll 1
  for (int t = 0; t < len; ++t) {
    const int jt = jt_lo + t;
    const int cur = t & 1;
    const bool more = (t + 1) < len;
    const int jbase = jt * BC;
    if (more) stage_load(jt + 1);

    const int kb = KB(cur), vb = VB(cur);

    floatx4 s[4];
#pragma unroll
    for (int ct = 0; ct < 4; ++ct) s[ct] = (floatx4)0.0f;
#pragma unroll
    for (int ks = 0; ks < 4; ++ks) {
#pragma unroll
      for (int ct = 0; ct < 4; ++ct) {
        short8 bf = *(const short8*)(smem + kb + (ct * 16 + nn) * KS_LD + ks * 32 + qd * 8);
        s[ct] = __builtin_amdgcn_mfma_f32_16x16x32_bf16(qf[ks], bf, s[ct], 0, 0, 0);
      }
    }

    {
      float tt[4][4];
      const bool needmask = flag && (jbase + BC - 1 > i0w);
#pragma unroll
      for (int ct = 0; ct < 4; ++ct)
#pragma unroll
        for (int r = 0; r < 4; ++r) {
          float tv = s[ct][r] * c1;
          if (needmask) {
            int jgl = jbase + ct * 16 + nn;
            int igl = i0w + qd * 4 + r;
            if (jgl > igl) tv = -3.0e38f;
          }
          tt[ct][r] = tv;
        }
#pragma unroll
      for (int r = 0; r < 4; ++r) {
        float mr = fmaxf(fmaxf(tt[0][r], tt[1][r]), fmaxf(tt[2][r], tt[3][r]));
        mr = rowmax16(mr);
        float mn = fmaxf(m[r], mr);
        float alpha = EXP2F(m[r] - mn);
        m[r] = mn;
        float ps = 0.0f;
#pragma unroll
        for (int ct = 0; ct < 4; ++ct) {
          float p = EXP2F(tt[ct][r] - mn);
          tt[ct][r] = p;
          ps += p;
        }
        l[r] = l[r] * alpha + ps;
#pragma unroll
        for (int vt = 0; vt < 8; ++vt) o[vt][r] *= alpha;
      }
#pragma unroll
      for (int ct = 0; ct < 4; ++ct)
#pragma unroll
        for (int r = 0; r < 4; ++r)
          smem[P0 + (w * 16 + qd * 4 + r) * PS_LD + ct * 16 + nn] = f2bf(tt[ct][r]);
    }

#pragma unroll
    for (int ks2 = 0; ks2 < 2; ++ks2) {
      short8 a = *(const short8*)(smem + P0 + (w * 16 + nn) * PS_LD + ks2 * 32 + qd * 8);
#pragma unroll
      for (int vt = 0; vt < 8; ++vt) {
        const int p = 16 * vt + rb + ((2 * vt + nn + hh) & 7);
        short8 vbf = *(const short8*)(smem + vb + p * VS_LD + ks2 * 32 + qd * 8);
        o[vt] = __builtin_amdgcn_mfma_f32_16x16x32_bf16(a, vbf, o[vt], 0, 0, 0);
      }
    }

    if (more) stage_write(cur ^ 1, jt + 1);
    __syncthreads();
  }

#pragma unroll
  for (int r = 0; r < 4; ++r) l[r] = rowsum16(l[r]);

  if (direct) {
    float* Ob = Out + ((size_t)b * SEQ_N + i0w) * DIM_V;
#pragma unroll
    for (int r = 0; r < 4; ++r) {
      float inv = 1.0f / l[r];
      int row = qd * 4 + r;
#pragma unroll
      for (int vt = 0; vt < 8; ++vt)
        Ob[(size_t)row * DIM_V + vt * 16 + nn] = o[vt][r] * inv;
    }
  } else {
    const int p = b * 16 + (rt - 16);
    const int slot = p * 2 + c;
    float* Op = ws + (size_t)slot * 64 * 128;
#pragma unroll
    for (int r = 0; r < 4; ++r) {
      int row = w * 16 + qd * 4 + r;
#pragma unroll
      for (int vt = 0; vt < 8; ++vt)
        Op[(size_t)row * 128 + vt * 16 + nn] = o[vt][r];
    }
    if (nn == 0) {
#pragma unroll
      for (int r = 0; r < 4; ++r) {
        int row = w * 16 + qd * 4 + r;
        ws[WS_M_OFF + slot * 64 + row] = m[r];
        ws[WS_L_OFF + slot * 64 + row] = l[r];
      }
    }
  }
}

__global__ __launch_bounds__(256, 2)
void fa_chunk(const float* __restrict__ Q, const float* __restrict__ K,
              const float* __restrict__ Vg, const int* __restrict__ kpl,
              const int* __restrict__ amask, float* __restrict__ Out,
              float* __restrict__ ws) {
  __shared__ __align__(16) ushort_t smem[SMEM_ELEMS];
  const int bx = blockIdx.x;
  const int b  = bx & 15;
  const int u  = bx >> 4;
  int rt, c;
  if (u < 16)      { rt = 16 + u; c = 0; }
  else if (u < 32) { rt = 47 - u; c = 1; }
  else             { rt = 47 - u; c = 0; }
  const int flag   = amask[0];
  const int mlimit = SEQ_M - kpl[b];
  const int ntiles = flag ? (rt + 1) : (SEQ_M / BC);
  const int jt_lo  = (c == 1) ? 16 : 0;
  const int jt_hi  = (c == 0 && rt >= 16) ? 16 : ntiles;
  process_chunk(Q, K, Vg, Out, ws, smem, b, rt, jt_lo, jt_hi, mlimit, flag, c, rt < 16);
}

__global__ __launch_bounds__(256)
void fa_merge(const float* __restrict__ ws, float* __restrict__ Out) {
  const int w = threadIdx.x >> 6, lane = threadIdx.x & 63;
  const int rowid = blockIdx.x * 4 + w;
  const int p = rowid >> 6, rr = rowid & 63;
  const int b = p >> 4, rt = 16 + (p & 15);
  float m1 = ws[WS_M_OFF + (p * 2 + 0) * 64 + rr];
  float l1 = ws[WS_L_OFF + (p * 2 + 0) * 64 + rr];
  float m2 = ws[WS_M_OFF + (p * 2 + 1) * 64 + rr];
  float l2 = ws[WS_L_OFF + (p * 2 + 1) * 64 + rr];
  float M  = fmaxf(m1, m2);
  float a1 = EXP2F(m1 - M), a2 = EXP2F(m2 - M);
  float inv = 1.0f / (l1 * a1 + l2 * a2);
  const float* O1 = ws + ((size_t)(p * 2 + 0) * 64 + rr) * 128;
  const float* O2 = ws + ((size_t)(p * 2 + 1) * 64 + rr) * 128;
  float2 x1 = *(const float2*)(O1 + lane * 2);
  float2 x2 = *(const float2*)(O2 + lane * 2);
  float2 r;
  r.x = (x1.x * a1 + x2.x * a2) * inv;
  r.y = (x1.y * a1 + x2.y * a2) * inv;
  *(float2*)(Out + ((size_t)b * SEQ_N + rt * 64 + rr) * 128 + lane * 2) = r;
}

__global__ __launch_bounds__(256, 2)
void fa_paired(const float* __restrict__ Q, const float* __restrict__ K,
               const float* __restrict__ Vg, const int* __restrict__ kpl,
               const int* __restrict__ amask, float* __restrict__ Out) {
  __shared__ __align__(16) ushort_t smem[SMEM_ELEMS];
  const int bx = blockIdx.x;
  const int b  = bx & 15;
  const int pp = bx >> 4;
  const int flag   = amask[0];
  const int mlimit = SEQ_M - kpl[b];
#pragma unroll 1
  for (int ph = 0; ph < 2; ++ph) {
    const int rt = ph ? (31 - pp) : pp;
    const int ntiles = flag ? (rt + 1) : (SEQ_M / BC);
    process_chunk(Q, K, Vg, Out, nullptr, smem, b, rt, 0, ntiles, mlimit, flag, 0, true);
  }
}

extern "C" void kernel_launch(void* const* d_in, const int* in_sizes, int n_in,
                              void* d_out, int out_size, void* d_ws, size_t ws_size,
                              hipStream_t stream) {
  const float* Q   = (const float*)d_in[0];
  const float* K   = (const float*)d_in[1];
  const float* V   = (const float*)d_in[2];
  const int* kpl   = (const int*)d_in[3];
  const int* amask = (const int*)d_in[4];
  float* O         = (float*)d_out;
  float* ws        = (float*)d_ws;

  int mode = -1;
  int grid = 0;
  size_t mloff = 0, lloff = 0;
  if (ws_size >= 41533440ull)      { mode = 2; grid = 1248; mloff = 10223616; lloff = 10303488; }
  else if (ws_size >= 35143680ull) { mode = 1; grid = 1056; mloff = 8650752;  lloff = 8718336;  }
  else if (ws_size >= 34078720ull) { mode = 0; grid = 1024; mloff = 8388608;  lloff = 8454144;  }

  if (mode >= 0) {
    float* PO = ws + WS2_PO;
    float* MP = ws + mloff;
    float* LP = ws + lloff;
    hipLaunchKernelGGL(prep2, dim3(3072), dim3(256), 0, stream, K, V, kpl, ws);
    hipLaunchKernelGGL(fa2, dim3(grid), dim3(256), 0, stream, Q, amask, O, ws, PO, MP, LP, mode);
    hipLaunchKernelGGL(fa2_merge, dim3(8192), dim3(256), 0, stream, O, PO, MP, LP, amask, mode);
  } else if (ws_size >= (size_t)WS_FLOATS * 4) {
    hipLaunchKernelGGL(fa_chunk, dim3(768), dim3(256), 0, stream, Q, K, V, kpl, amask, O, ws);
    hipLaunchKernelGGL(fa_merge, dim3(4096), dim3(256), 0, stream, ws, O);
  } else {
    hipLaunchKernelGGL(fa_paired, dim3(256), dim3(256), 0, stream, Q, K, V, kpl, amask, O);
  }
}

// Round 7
// 142.990 us; speedup vs baseline: 1.1447x; 1.0766x over previous
//
#include <hip/hip_runtime.h>
#include <stdint.h>

typedef unsigned short ushort_t;
typedef __attribute__((ext_vector_type(8))) short short8;   // 8 x bf16 (4 VGPRs)
typedef __attribute__((ext_vector_type(4))) float floatx4;  // MFMA accum

#define SEQ_N 2048
#define SEQ_M 2048
#define DIM_D 128
#define DIM_V 128
#define BC 64    // keys per tile (OLD path)
#define BC2 32   // keys per tile (NEW path)

// ======================= common helpers =======================

#if __has_builtin(__builtin_amdgcn_exp2f)
#define EXP2F(x) __builtin_amdgcn_exp2f(x)
#else
#define EXP2F(x) exp2f(x)
#endif

template <int CTRL>
__device__ __forceinline__ float dpp_f(float x) {
  int xi = __builtin_bit_cast(int, x);
  int yi = __builtin_amdgcn_update_dpp(xi, xi, CTRL, 0xf, 0xf, false);
  return __builtin_bit_cast(float, yi);
}
__device__ __forceinline__ float rowmax16(float x) {
  x = fmaxf(x, dpp_f<0x128>(x));
  x = fmaxf(x, dpp_f<0x124>(x));
  x = fmaxf(x, dpp_f<0x122>(x));
  x = fmaxf(x, dpp_f<0x121>(x));
  return x;
}
__device__ __forceinline__ float rowsum16(float x) {
  x += dpp_f<0x128>(x);
  x += dpp_f<0x124>(x);
  x += dpp_f<0x122>(x);
  x += dpp_f<0x121>(x);
  return x;
}

__device__ __forceinline__ ushort_t f2bf(float f) {
  uint32_t u = __builtin_bit_cast(uint32_t, f);
  return (ushort_t)((u + 0x8000u) >> 16);
}
// pack two fp32 -> bf16 pair in ONE v_perm (3 VALU total, bit-identical to f2bf pair)
__device__ __forceinline__ uint32_t bfpack(float lo, float hi) {
  uint32_t a = __builtin_bit_cast(uint32_t, lo) + 0x8000u;
  uint32_t b = __builtin_bit_cast(uint32_t, hi) + 0x8000u;
  return __builtin_amdgcn_perm(b, a, 0x07060302u);  // {b[31:16], a[31:16]}
}

// ======================= NEW PATH =======================
// BM=64 rows/block, BC2=32 keys/tile, 256 threads (4 waves x 16 rows).
// SWAPPED QK^T: S^T = mfma(A=K, B=Q) puts P[q=nn][8 keys] lane-local in the
// exact A-fragment order PV needs -> softmax fully in-register, NO P LDS.
// V's k-order permutation (stored kk holds physical key pk(kk) =
// ((kk>>2)&1)*16 + (kk>>3)*4 + (kk&3)) is baked into prep2's Vt layout.
// LDS (ushort): K 2x[32][128] (8KB ea), Vt 2x[128][32] (8KB ea) = 32768 B.
// Schedule: proven mode0 map (1024 blocks, nch=2 per row-block).
#define K2OFF 0
#define V2OFF 8192
#define SMEM2 16384
#define KELEMS 4096
#define VELEMS 4096

// ws layout (floats): Kb bf16 [16][2048][128], Vt bf16 [16][128][2048] (permuted),
// PO 512 partial-O slots x 64x128 fp32, M/L 1024 chunks x 64 rows.
#define WS2_KB 0
#define WS2_VT 2097152
#define WS2_PO 4194304
#define WS2_M  8388608
#define WS2_L  8454144
#define WS2_FLOATS 8519680   // * 4 = 34078720 bytes (gate, proven available)

// async 16B global->LDS; lds_base must be wave-uniform (HW adds lane*16)
__device__ __forceinline__ void stage16(const ushort_t* src, ushort_t* lds_base, int lane) {
#if __has_builtin(__builtin_amdgcn_global_load_lds)
  __builtin_amdgcn_global_load_lds(
      (const __attribute__((address_space(1))) void*)src,
      (__attribute__((address_space(3))) void*)lds_base, 16, 0, 0);
#else
  *(uint4*)(lds_base + lane * 8) = *(const uint4*)src;
#endif
}

// prep: K -> bf16 (+ padding mask), V -> bf16 transposed [b][v][m] with the
// per-32-block k-permutation baked in (write-side column remap, 6 VALU/thread).
__global__ __launch_bounds__(256)
void prep2(const float* __restrict__ K, const float* __restrict__ Vg,
           const int* __restrict__ kpl, float* __restrict__ ws) {
  __shared__ __align__(16) ushort_t lt[64][72];
  ushort_t* Kb = (ushort_t*)(ws + WS2_KB);
  ushort_t* Vt = (ushort_t*)(ws + WS2_VT);
  const int g = blockIdx.x, tid = threadIdx.x;
  if (g < 2048) {
    const size_t e = (size_t)g * 2048 + (size_t)tid * 8;
    const int row = (int)(e >> 7);
    const int b = row >> 11, mm = row & 2047;
    const int mlimit = SEQ_M - kpl[b];
    uint4 kw = make_uint4(0u, 0u, 0u, 0u);
    if (mm < mlimit) {
      const float* p = K + e;
      float4 f0 = *(const float4*)p, f1 = *(const float4*)(p + 4);
      kw.x = bfpack(f0.x, f0.y); kw.y = bfpack(f0.z, f0.w);
      kw.z = bfpack(f1.x, f1.y); kw.w = bfpack(f1.z, f1.w);
    }
    *(uint4*)(Kb + e) = kw;
  } else {
    const int g2 = g - 2048;
    const int b = g2 >> 6;
    const int mt = (g2 & 63) >> 1;
    const int vh = (g2 & 1) * 64;
    const int mrow = tid >> 2, v0 = (tid & 3) * 16;
    // write-side column remap: stored col kk holds physical key pk(kk);
    // inverse: physical pm goes to kk = ((pm>>2)&3)*8 + ((pm>>4)&1)*4 + (pm&3)
    const int pm = mrow & 31;
    const int mcol = (mrow & 32) + (((pm >> 2) & 3) << 3)
                   + (((pm >> 4) & 1) << 2) + (pm & 3);
    const float* p = Vg + ((size_t)b * SEQ_M + (size_t)(mt * 64 + mrow)) * DIM_V + vh + v0;
    float4 f0 = *(const float4*)p, f1 = *(const float4*)(p + 4);
    float4 f2 = *(const float4*)(p + 8), f3 = *(const float4*)(p + 12);
    lt[v0 +  0][mcol] = f2bf(f0.x); lt[v0 +  1][mcol] = f2bf(f0.y);
    lt[v0 +  2][mcol] = f2bf(f0.z); lt[v0 +  3][mcol] = f2bf(f0.w);
    lt[v0 +  4][mcol] = f2bf(f1.x); lt[v0 +  5][mcol] = f2bf(f1.y);
    lt[v0 +  6][mcol] = f2bf(f1.z); lt[v0 +  7][mcol] = f2bf(f1.w);
    lt[v0 +  8][mcol] = f2bf(f2.x); lt[v0 +  9][mcol] = f2bf(f2.y);
    lt[v0 + 10][mcol] = f2bf(f2.z); lt[v0 + 11][mcol] = f2bf(f2.w);
    lt[v0 + 12][mcol] = f2bf(f3.x); lt[v0 + 13][mcol] = f2bf(f3.y);
    lt[v0 + 14][mcol] = f2bf(f3.z); lt[v0 + 15][mcol] = f2bf(f3.w);
    __syncthreads();
    const int v = tid >> 2, mo = (tid & 3) * 16;
    ushort_t* dst = Vt + ((size_t)(b * DIM_V + vh + v) * SEQ_M) + mt * 64 + mo;
    *(uint4*)(dst + 0) = *(const uint4*)&lt[v][mo];
    *(uint4*)(dst + 8) = *(const uint4*)&lt[v][mo + 8];
  }
}

__global__ __launch_bounds__(256, 4)
void fa2(const float* __restrict__ Q, const int* __restrict__ amask,
         float* __restrict__ Out, float* __restrict__ ws,
         float* __restrict__ PO, float* __restrict__ MP, float* __restrict__ LP) {
  __shared__ __align__(16) ushort_t sm[SMEM2];
  const ushort_t* __restrict__ Kb = (const ushort_t*)(ws + WS2_KB);
  const ushort_t* __restrict__ Vt = (const ushort_t*)(ws + WS2_VT);

  const int tid = threadIdx.x;
  const int lane = tid & 63;
  const int w = tid >> 6;               // 0..3
  const int qd = lane >> 4;
  const int nn = lane & 15;

  const int bx = blockIdx.x;
  const int xcd = bx & 7;
  const int q = bx >> 3;
  const int flag = amask[0];

  // proven mode0 map: 1024 blocks, complementary chunk lengths per CU slot
  const int s = q >> 5, v5 = q & 31, pz = v5 & 1, j = v5 >> 1;
  const int b = xcd * 2 + pz;
  const int jj = pz ? (15 - j) : j;
  int rt, c;
  if (s == 0)      { rt = jj;      c = 0; }
  else if (s == 1) { rt = 31 - jj; c = 0; }
  else if (s == 2) { rt = 16 + jj; c = 1; }
  else             { rt = 15 - jj; c = 1; }

  const int ntf = flag ? (2 * rt + 2) : (SEQ_M / BC2);
  const int sp  = flag ? (rt + 1) : (SEQ_M / BC2 / 2);
  const int jt_lo = c ? sp : 0;
  const int jt_hi = c ? ntf : sp;

  const int i0w = rt * 64 + w * 16;
  const int qgl = i0w + nn;             // this lane's P-side query (global row)
  const float c1 = 0.08838834764831845f * 1.4426950408889634f;  // scale*log2e

  // ---- Q fragments (bf16; used as the B operand of swapped QK^T) ----
  short8 qf[4];
  {
    const float* Qb = Q + ((size_t)b * SEQ_N + (size_t)qgl) * DIM_D;
    union { short8 v; uint32_t u32[4]; } tq;
#pragma unroll
    for (int ks = 0; ks < 4; ++ks) {
      const float* pq = Qb + ks * 32 + qd * 8;
      float4 f0 = *(const float4*)pq, f1 = *(const float4*)(pq + 4);
      tq.u32[0] = bfpack(f0.x, f0.y);
      tq.u32[1] = bfpack(f0.z, f0.w);
      tq.u32[2] = bfpack(f1.x, f1.y);
      tq.u32[3] = bfpack(f1.z, f1.w);
      qf[ks] = tq.v;
    }
  }

  floatx4 o[8];
#pragma unroll
  for (int vt = 0; vt < 8; ++vt) o[vt] = (floatx4)0.0f;
  float m = -3.0e38f, l = 0.0f;         // P-side state (query nn)
  float m_o[4];                          // O-side replicas (queries qd*4+r)
#pragma unroll
  for (int r = 0; r < 4; ++r) m_o[r] = -3.0e38f;

  const size_t kbatch = (size_t)b * (SEQ_M * DIM_D);
  const size_t vbatch = (size_t)b * ((size_t)DIM_V * SEQ_M);

  // async stage of one K tile (32x128) + one V^T tile (128x32) into buf.
  // LDS linear; swizzles applied on the GLOBAL source (m173): K granule
  // ^= (row&7), V granule (of 4 per 64B row) ^= (row>>2)&3.
  auto stage = [&](int buf, int jt) {
    const int jb = jt * BC2;
#pragma unroll
    for (int i = 0; i < 2; ++i) {
      const int seg = w * 2 + i;                 // 0..7 (1KB segments)
      {
        const int rrow = seg * 4 + (lane >> 4);  // K row in tile (32 rows x 256B)
        const int col  = ((lane & 15) * 8) ^ ((rrow & 7) << 3);
        const ushort_t* src = Kb + kbatch + ((size_t)(jb + rrow) << 7) + col;
        stage16(src, &sm[K2OFF + buf * KELEMS + seg * 512], lane);
      }
      {
        const int vrow = seg * 16 + (lane >> 2); // V^T row (128 rows x 64B)
        const int colg = (lane & 3) ^ ((lane >> 4) & 3);  // == (lane&3)^((vrow>>2)&3)
        const ushort_t* src = Vt + vbatch + ((size_t)vrow << 11) + jb + colg * 8;
        stage16(src, &sm[V2OFF + buf * VELEMS + seg * 512], lane);
      }
    }
  };

  stage(0, jt_lo);
  __syncthreads();

  const int len = jt_hi - jt_lo;
  const int swl = (nn & 7) << 3;          // K read swizzle (row&7 == nn&7)
  const int vsw = ((nn >> 2) & 3) << 3;   // V read swizzle ((row>>2)&3)
#pragma unroll 1
  for (int t = 0; t < len; ++t) {
    const int cur = t & 1;
    const int jbase = (jt_lo + t) * BC2;
    if (t + 1 < len) stage(cur ^ 1, jt_lo + t + 1);

    const int kb = K2OFF + cur * KELEMS;
    const int vb = V2OFF + cur * VELEMS;

    // ---- S^T = K Q^T : lane (qd,nn) gets S[key=ct*16+qd*4+r][query=nn] ----
    floatx4 sx[2];
#pragma unroll
    for (int ct = 0; ct < 2; ++ct) sx[ct] = (floatx4)0.0f;
    __builtin_amdgcn_s_setprio(1);
#pragma unroll
    for (int ks = 0; ks < 4; ++ks) {
#pragma unroll
      for (int ct = 0; ct < 2; ++ct) {
        short8 kf = *(const short8*)&sm[kb + (ct * 16 + nn) * 128
                                        + ((ks * 32 + qd * 8) ^ swl)];
        sx[ct] = __builtin_amdgcn_mfma_f32_16x16x32_bf16(kf, qf[ks], sx[ct], 0, 0, 0);
      }
    }
    __builtin_amdgcn_s_setprio(0);

    // ---- in-register online softmax (defer-max, THR=8) ----
    const bool needmask = flag && (jbase + BC2 - 1 > i0w);
    if (needmask) {
#pragma unroll
      for (int ct = 0; ct < 2; ++ct) {
        const int kbase = jbase + ct * 16 + qd * 4 - qgl;
#pragma unroll
        for (int r = 0; r < 4; ++r) {
          const float tv = sx[ct][r] * c1;
          sx[ct][r] = (kbase + r > 0) ? -3.0e38f : tv;
        }
      }
    } else {
#pragma unroll
      for (int ct = 0; ct < 2; ++ct)
#pragma unroll
        for (int r = 0; r < 4; ++r) sx[ct][r] *= c1;
    }
    float mr = fmaxf(fmaxf(fmaxf(sx[0][0], sx[0][1]), fmaxf(sx[0][2], sx[0][3])),
                     fmaxf(fmaxf(sx[1][0], sx[1][1]), fmaxf(sx[1][2], sx[1][3])));
    mr = fmaxf(mr, __shfl_xor(mr, 16));
    mr = fmaxf(mr, __shfl_xor(mr, 32));

    if (__any((mr > m + 8.0f) ? 1 : 0)) {
      const float mn = fmaxf(m, mr);
      l *= EXP2F(m - mn);
      m = mn;
#pragma unroll
      for (int r = 0; r < 4; ++r) {
        // fetch the new max of O-side query qd*4+r from the lane that owns it
        const float mo_n = __shfl(mn, (qd << 4) + qd * 4 + r);
        const float al = EXP2F(m_o[r] - mo_n);
        m_o[r] = mo_n;
#pragma unroll
        for (int vt = 0; vt < 8; ++vt) o[vt][r] *= al;
      }
    }

    float p[2][4];
#pragma unroll
    for (int ct = 0; ct < 2; ++ct)
#pragma unroll
      for (int r = 0; r < 4; ++r) {
        p[ct][r] = EXP2F(sx[ct][r] - m);
        l += p[ct][r];
      }
    union { short8 v; uint32_t u[4]; } pa;   // A-fragment: elem j = key kk=qd*8+j
    pa.u[0] = bfpack(p[0][0], p[0][1]);
    pa.u[1] = bfpack(p[0][2], p[0][3]);
    pa.u[2] = bfpack(p[1][0], p[1][1]);
    pa.u[3] = bfpack(p[1][2], p[1][3]);

    // ---- O += P V (P in registers; V k-permuted in Vt layout) ----
    __builtin_amdgcn_s_setprio(1);
#pragma unroll
    for (int vt = 0; vt < 8; ++vt) {
      short8 vbf = *(const short8*)&sm[vb + (vt * 16 + nn) * 32 + ((qd * 8) ^ vsw)];
      o[vt] = __builtin_amdgcn_mfma_f32_16x16x32_bf16(pa.v, vbf, o[vt], 0, 0, 0);
    }
    __builtin_amdgcn_s_setprio(0);

    __syncthreads();
  }

  // ---- epilogue: unnormalized partial + (m,l); merge normalizes ----
  l += __shfl_xor(l, 16);
  l += __shfl_xor(l, 32);

  const int cid = (b * 32 + rt) * 2 + c;
  const int slotb = b * 32 + rt;
  if (c == 0) {
    float* Od = Out + ((size_t)b * SEQ_N + i0w) * DIM_V;
#pragma unroll
    for (int r = 0; r < 4; ++r) {
      const int row = qd * 4 + r;
#pragma unroll
      for (int vt = 0; vt < 8; ++vt)
        Od[(size_t)row * DIM_V + vt * 16 + nn] = o[vt][r];
    }
  } else {
    float* Od = PO + (size_t)slotb * (64 * DIM_V);
#pragma unroll
    for (int r = 0; r < 4; ++r) {
      const int row = w * 16 + qd * 4 + r;
#pragma unroll
      for (int vt = 0; vt < 8; ++vt)
        Od[(size_t)row * DIM_V + vt * 16 + nn] = o[vt][r];
    }
  }
  if (lane < 16) {   // qd==0 lanes hold (m, l) for query nn
    MP[cid * 64 + w * 16 + nn] = m;
    LP[cid * 64 + w * 16 + nn] = l;
  }
}

// merge the two chunks of every row (exp2-domain flash combine; chunk0 in Out)
__global__ __launch_bounds__(256)
void fa2_merge(float* __restrict__ Out, const float* __restrict__ PO,
               const float* __restrict__ MP, const float* __restrict__ LP) {
  const int w = threadIdx.x >> 6, lane = threadIdx.x & 63;
  const int rowid = blockIdx.x * 4 + w;        // 0..32767
  const int rb = rowid >> 6, rr = rowid & 63;  // rb 0..511
  const int b = rb >> 5, rt = rb & 31;
  const float m1 = MP[(rb * 2 + 0) * 64 + rr];
  const float l1 = LP[(rb * 2 + 0) * 64 + rr];
  const float m2 = MP[(rb * 2 + 1) * 64 + rr];
  const float l2 = LP[(rb * 2 + 1) * 64 + rr];
  const float M = fmaxf(m1, m2);
  const float a1 = EXP2F(m1 - M), a2 = EXP2F(m2 - M);
  const float inv = 1.0f / (l1 * a1 + l2 * a2);
  float* O1 = Out + ((size_t)b * SEQ_N + (size_t)rt * 64 + rr) * DIM_V;
  const float* O2 = PO + (size_t)rb * (64 * DIM_V) + (size_t)rr * DIM_V;
  float2 x1 = *(const float2*)(O1 + lane * 2);
  float2 x2 = *(const float2*)(O2 + lane * 2);
  float2 r;
  r.x = (x1.x * a1 + x2.x * a2) * inv;
  r.y = (x1.y * a1 + x2.y * a2) * inv;
  *(float2*)(O1 + lane * 2) = r;
}

// ======================= OLD PATH (verified fallback) =======================

#define KS_LD 136
#define VS_LD 72
#define PS_LD 72
#define KB(i) ((i) * 8704)
#define VB(i) (17408 + (i) * 9216)
#define P0 35840
#define SMEM_ELEMS 40448

#define WS_O_FLOATS (256 * 2 * 64 * 128)
#define WS_M_OFF    WS_O_FLOATS
#define WS_L_OFF    (WS_O_FLOATS + 32768)
#define WS_FLOATS   (WS_O_FLOATS + 65536)

__device__ __forceinline__ void process_chunk(
    const float* __restrict__ Q, const float* __restrict__ K,
    const float* __restrict__ Vg, float* __restrict__ Out,
    float* __restrict__ ws, ushort_t* __restrict__ smem,
    int b, int rt, int jt_lo, int jt_hi, int mlimit, int flag, int c, bool direct) {
  const int tid  = threadIdx.x;
  const int lane = tid & 63;
  const int w    = tid >> 6;
  const int qd   = lane >> 4;
  const int nn   = lane & 15;

  const float c1 = 0.08838834764831845f * 1.4426950408889634f;

  const int oct = tid & 15;
  const int j0  = (tid >> 4) * 4;
  const int hh  = nn >> 3;
  const int rb  = 8 * hh;

  const int i0w = rt * 64 + w * 16;
  const size_t koff = (size_t)b * SEQ_M * DIM_D;
  const size_t voff = (size_t)b * SEQ_M * DIM_V;

  short8 qf[4];
  {
    const float* Qb = Q + ((size_t)b * SEQ_N + (size_t)(i0w + nn)) * DIM_D;
    union { short8 v; uint32_t u32[4]; } t;
#pragma unroll
    for (int ks = 0; ks < 4; ++ks) {
      const float* p = Qb + ks * 32 + qd * 8;
      float4 f0 = *(const float4*)p, f1 = *(const float4*)(p + 4);
      t.u32[0] = bfpack(f0.x, f0.y);
      t.u32[1] = bfpack(f0.z, f0.w);
      t.u32[2] = bfpack(f1.x, f1.y);
      t.u32[3] = bfpack(f1.z, f1.w);
      qf[ks] = t.v;
    }
  }

  floatx4 o[8];
#pragma unroll
  for (int vt = 0; vt < 8; ++vt) o[vt] = (floatx4)0.0f;
  float m[4], l[4];
#pragma unroll
  for (int r = 0; r < 4; ++r) { m[r] = -3.0e38f; l[r] = 0.0f; }

  float4 kr[4][2], vr[4][2];

  auto stage_load = [&](int jt) {
    const int jbase = jt * BC;
#pragma unroll
    for (int r = 0; r < 4; ++r) {
      const float* kp = K  + koff + (size_t)(jbase + j0 + r) * DIM_D + oct * 8;
      kr[r][0] = *(const float4*)kp;  kr[r][1] = *(const float4*)(kp + 4);
      const float* vp = Vg + voff + (size_t)(jbase + j0 + r) * DIM_V + oct * 8;
      vr[r][0] = *(const float4*)vp;  vr[r][1] = *(const float4*)(vp + 4);
    }
  };

  auto stage_write = [&](int buf, int jt) {
    const int jbase = jt * BC;
    const int kb = KB(buf), vb = VB(buf);
#pragma unroll
    for (int r = 0; r < 4; ++r) {
      uint4 kw;
      kw.x = bfpack(kr[r][0].x, kr[r][0].y);
      kw.y = bfpack(kr[r][0].z, kr[r][0].w);
      kw.z = bfpack(kr[r][1].x, kr[r][1].y);
      kw.w = bfpack(kr[r][1].z, kr[r][1].w);
      if (jbase + j0 + r >= mlimit) kw = make_uint4(0u, 0u, 0u, 0u);
      *(uint4*)(smem + kb + (j0 + r) * KS_LD + oct * 8) = kw;
    }
    float vc[4][8];
#pragma unroll
    for (int r = 0; r < 4; ++r) {
      vc[r][0]=vr[r][0].x; vc[r][1]=vr[r][0].y; vc[r][2]=vr[r][0].z; vc[r][3]=vr[r][0].w;
      vc[r][4]=vr[r][1].x; vc[r][5]=vr[r][1].y; vc[r][6]=vr[r][1].z; vc[r][7]=vr[r][1].w;
    }
#pragma unroll
    for (int q = 0; q < 8; ++q) {
      const int p = 8 * oct + ((oct + q) & 7);
      uint2 dv;
      dv.x = bfpack(vc[0][q], vc[1][q]);
      dv.y = bfpack(vc[2][q], vc[3][q]);
      *(uint2*)(smem + vb + p * VS_LD + j0) = dv;
    }
  };

  stage_load(jt_lo);
  stage_write(0, jt_lo);
  __syncthreads();

  const int len = jt_hi - jt_lo;
#pragma unroll 1
  for (int t = 0; t < len; ++t) {
    const int jt = jt_lo + t;
    const int cur = t & 1;
    const bool more = (t + 1) < len;
    const int jbase = jt * BC;
    if (more) stage_load(jt + 1);

    const int kb = KB(cur), vb = VB(cur);

    floatx4 s[4];
#pragma unroll
    for (int ct = 0; ct < 4; ++ct) s[ct] = (floatx4)0.0f;
#pragma unroll
    for (int ks = 0; ks < 4; ++ks) {
#pragma unroll
      for (int ct = 0; ct < 4; ++ct) {
        short8 bf = *(const short8*)(smem + kb + (ct * 16 + nn) * KS_LD + ks * 32 + qd * 8);
        s[ct] = __builtin_amdgcn_mfma_f32_16x16x32_bf16(qf[ks], bf, s[ct], 0, 0, 0);
      }
    }

    {
      float tt[4][4];
      const bool needmask = flag && (jbase + BC - 1 > i0w);
#pragma unroll
      for (int ct = 0; ct < 4; ++ct)
#pragma unroll
        for (int r = 0; r < 4; ++r) {
          float tv = s[ct][r] * c1;
          if (needmask) {
            int jgl = jbase + ct * 16 + nn;
            int igl = i0w + qd * 4 + r;
            if (jgl > igl) tv = -3.0e38f;
          }
          tt[ct][r] = tv;
        }
#pragma unroll
      for (int r = 0; r < 4; ++r) {
        float mr = fmaxf(fmaxf(tt[0][r], tt[1][r]), fmaxf(tt[2][r], tt[3][r]));
        mr = rowmax16(mr);
        float mn = fmaxf(m[r], mr);
        float alpha = EXP2F(m[r] - mn);
        m[r] = mn;
        float ps = 0.0f;
#pragma unroll
        for (int ct = 0; ct < 4; ++ct) {
          float p = EXP2F(tt[ct][r] - mn);
          tt[ct][r] = p;
          ps += p;
        }
        l[r] = l[r] * alpha + ps;
#pragma unroll
        for (int vt = 0; vt < 8; ++vt) o[vt][r] *= alpha;
      }
#pragma unroll
      for (int ct = 0; ct < 4; ++ct)
#pragma unroll
        for (int r = 0; r < 4; ++r)
          smem[P0 + (w * 16 + qd * 4 + r) * PS_LD + ct * 16 + nn] = f2bf(tt[ct][r]);
    }

#pragma unroll
    for (int ks2 = 0; ks2 < 2; ++ks2) {
      short8 a = *(const short8*)(smem + P0 + (w * 16 + nn) * PS_LD + ks2 * 32 + qd * 8);
#pragma unroll
      for (int vt = 0; vt < 8; ++vt) {
        const int p = 16 * vt + rb + ((2 * vt + nn + hh) & 7);
        short8 vbf = *(const short8*)(smem + vb + p * VS_LD + ks2 * 32 + qd * 8);
        o[vt] = __builtin_amdgcn_mfma_f32_16x16x32_bf16(a, vbf, o[vt], 0, 0, 0);
      }
    }

    if (more) stage_write(cur ^ 1, jt + 1);
    __syncthreads();
  }

#pragma unroll
  for (int r = 0; r < 4; ++r) l[r] = rowsum16(l[r]);

  if (direct) {
    float* Ob = Out + ((size_t)b * SEQ_N + i0w) * DIM_V;
#pragma unroll
    for (int r = 0; r < 4; ++r) {
      float inv = 1.0f / l[r];
      int row = qd * 4 + r;
#pragma unroll
      for (int vt = 0; vt < 8; ++vt)
        Ob[(size_t)row * DIM_V + vt * 16 + nn] = o[vt][r] * inv;
    }
  } else {
    const int p = b * 16 + (rt - 16);
    const int slot = p * 2 + c;
    float* Op = ws + (size_t)slot * 64 * 128;
#pragma unroll
    for (int r = 0; r < 4; ++r) {
      int row = w * 16 + qd * 4 + r;
#pragma unroll
      for (int vt = 0; vt < 8; ++vt)
        Op[(size_t)row * 128 + vt * 16 + nn] = o[vt][r];
    }
    if (nn == 0) {
#pragma unroll
      for (int r = 0; r < 4; ++r) {
        int row = w * 16 + qd * 4 + r;
        ws[WS_M_OFF + slot * 64 + row] = m[r];
        ws[WS_L_OFF + slot * 64 + row] = l[r];
      }
    }
  }
}

__global__ __launch_bounds__(256, 2)
void fa_chunk(const float* __restrict__ Q, const float* __restrict__ K,
              const float* __restrict__ Vg, const int* __restrict__ kpl,
              const int* __restrict__ amask, float* __restrict__ Out,
              float* __restrict__ ws) {
  __shared__ __align__(16) ushort_t smem[SMEM_ELEMS];
  const int bx = blockIdx.x;
  const int b  = bx & 15;
  const int u  = bx >> 4;
  int rt, c;
  if (u < 16)      { rt = 16 + u; c = 0; }
  else if (u < 32) { rt = 47 - u; c = 1; }
  else             { rt = 47 - u; c = 0; }
  const int flag   = amask[0];
  const int mlimit = SEQ_M - kpl[b];
  const int ntiles = flag ? (rt + 1) : (SEQ_M / BC);
  const int jt_lo  = (c == 1) ? 16 : 0;
  const int jt_hi  = (c == 0 && rt >= 16) ? 16 : ntiles;
  process_chunk(Q, K, Vg, Out, ws, smem, b, rt, jt_lo, jt_hi, mlimit, flag, c, rt < 16);
}

__global__ __launch_bounds__(256)
void fa_merge(const float* __restrict__ ws, float* __restrict__ Out) {
  const int w = threadIdx.x >> 6, lane = threadIdx.x & 63;
  const int rowid = blockIdx.x * 4 + w;
  const int p = rowid >> 6, rr = rowid & 63;
  const int b = p >> 4, rt = 16 + (p & 15);
  float m1 = ws[WS_M_OFF + (p * 2 + 0) * 64 + rr];
  float l1 = ws[WS_L_OFF + (p * 2 + 0) * 64 + rr];
  float m2 = ws[WS_M_OFF + (p * 2 + 1) * 64 + rr];
  float l2 = ws[WS_L_OFF + (p * 2 + 1) * 64 + rr];
  float M  = fmaxf(m1, m2);
  float a1 = EXP2F(m1 - M), a2 = EXP2F(m2 - M);
  float inv = 1.0f / (l1 * a1 + l2 * a2);
  const float* O1 = ws + ((size_t)(p * 2 + 0) * 64 + rr) * 128;
  const float* O2 = ws + ((size_t)(p * 2 + 1) * 64 + rr) * 128;
  float2 x1 = *(const float2*)(O1 + lane * 2);
  float2 x2 = *(const float2*)(O2 + lane * 2);
  float2 r;
  r.x = (x1.x * a1 + x2.x * a2) * inv;
  r.y = (x1.y * a1 + x2.y * a2) * inv;
  *(float2*)(Out + ((size_t)b * SEQ_N + rt * 64 + rr) * 128 + lane * 2) = r;
}

__global__ __launch_bounds__(256, 2)
void fa_paired(const float* __restrict__ Q, const float* __restrict__ K,
               const float* __restrict__ Vg, const int* __restrict__ kpl,
               const int* __restrict__ amask, float* __restrict__ Out) {
  __shared__ __align__(16) ushort_t smem[SMEM_ELEMS];
  const int bx = blockIdx.x;
  const int b  = bx & 15;
  const int pp = bx >> 4;
  const int flag   = amask[0];
  const int mlimit = SEQ_M - kpl[b];
#pragma unroll 1
  for (int ph = 0; ph < 2; ++ph) {
    const int rt = ph ? (31 - pp) : pp;
    const int ntiles = flag ? (rt + 1) : (SEQ_M / BC);
    process_chunk(Q, K, Vg, Out, nullptr, smem, b, rt, 0, ntiles, mlimit, flag, 0, true);
  }
}

extern "C" void kernel_launch(void* const* d_in, const int* in_sizes, int n_in,
                              void* d_out, int out_size, void* d_ws, size_t ws_size,
                              hipStream_t stream) {
  const float* Q   = (const float*)d_in[0];
  const float* K   = (const float*)d_in[1];
  const float* V   = (const float*)d_in[2];
  const int* kpl   = (const int*)d_in[3];
  const int* amask = (const int*)d_in[4];
  float* O         = (float*)d_out;
  float* ws        = (float*)d_ws;

  if (ws_size >= (size_t)WS2_FLOATS * 4) {
    float* PO = ws + WS2_PO;
    float* MP = ws + WS2_M;
    float* LP = ws + WS2_L;
    hipLaunchKernelGGL(prep2, dim3(3072), dim3(256), 0, stream, K, V, kpl, ws);
    hipLaunchKernelGGL(fa2, dim3(1024), dim3(256), 0, stream, Q, amask, O, ws, PO, MP, LP);
    hipLaunchKernelGGL(fa2_merge, dim3(8192), dim3(256), 0, stream, O, PO, MP, LP);
  } else if (ws_size >= (size_t)WS_FLOATS * 4) {
    hipLaunchKernelGGL(fa_chunk, dim3(768), dim3(256), 0, stream, Q, K, V, kpl, amask, O, ws);
    hipLaunchKernelGGL(fa_merge, dim3(4096), dim3(256), 0, stream, ws, O);
  } else {
    hipLaunchKernelGGL(fa_paired, dim3(256), dim3(256), 0, stream, Q, K, V, kpl, amask, O);
  }
}